// Round 1
// baseline (504.079 us; speedup 1.0000x reference)
//
#include <hip/hip_runtime.h>
#include <hip/hip_bf16.h>

// Problem constants
// B=16, C=64, CQ=8, H=128, W=128
#define PADE 132   // Et row stride (128 + 4), multiple of 4 for b128 align
#define PADV 68    // vs row stride (64 + 4)

// ---------------------------------------------------------------------------
// Kernel 1: projections q,k (C->8), v (C->64). One thread per pixel.
// ---------------------------------------------------------------------------
__global__ __launch_bounds__(256) void proj_kernel(
    const float* __restrict__ x,
    const float* __restrict__ Wq, const float* __restrict__ bq,
    const float* __restrict__ Wk, const float* __restrict__ bk,
    const float* __restrict__ Wv, const float* __restrict__ bv,
    float* __restrict__ q, float* __restrict__ k, float* __restrict__ v)
{
    __shared__ __align__(16) float sWv[64 * 64];
    __shared__ __align__(16) float sWq[8 * 64];
    __shared__ __align__(16) float sWk[8 * 64];
    __shared__ float sbias[80];

    int t = threadIdx.x;
    for (int i = t; i < 4096; i += 256) sWv[i] = Wv[i];
    for (int i = t; i < 512; i += 256) { sWq[i] = Wq[i]; sWk[i] = Wk[i]; }
    if (t < 64) sbias[t] = bv[t];
    else if (t < 72) sbias[t] = bq[t - 64];
    else if (t < 80) sbias[t] = bk[t - 72];
    __syncthreads();

    int pix = blockIdx.x * 256 + t;        // 0 .. 262143
    int b = pix >> 14;
    int hw = pix & 16383;
    const float* xp = x + ((long)b << 20) + hw;   // b*64*16384

    float accv[64], accq[8], acck[8];
#pragma unroll
    for (int o = 0; o < 64; o++) accv[o] = sbias[o];
#pragma unroll
    for (int o = 0; o < 8; o++) { accq[o] = sbias[64 + o]; acck[o] = sbias[72 + o]; }

    for (int c = 0; c < 64; c += 4) {
        float x0 = xp[(c + 0) * 16384];
        float x1 = xp[(c + 1) * 16384];
        float x2 = xp[(c + 2) * 16384];
        float x3 = xp[(c + 3) * 16384];
#pragma unroll
        for (int o = 0; o < 64; o++) {
            float4 wv = *(const float4*)&sWv[o * 64 + c];
            accv[o] += wv.x * x0 + wv.y * x1 + wv.z * x2 + wv.w * x3;
        }
#pragma unroll
        for (int o = 0; o < 8; o++) {
            float4 wq4 = *(const float4*)&sWq[o * 64 + c];
            accq[o] += wq4.x * x0 + wq4.y * x1 + wq4.z * x2 + wq4.w * x3;
            float4 wk4 = *(const float4*)&sWk[o * 64 + c];
            acck[o] += wk4.x * x0 + wk4.y * x1 + wk4.z * x2 + wk4.w * x3;
        }
    }

    long qbase = ((long)b << 17) + hw;     // b*8*16384
#pragma unroll
    for (int o = 0; o < 8; o++) {
        q[qbase + o * 16384] = accq[o];
        k[qbase + o * 16384] = acck[o];
    }
    long vbase = ((long)b << 20) + hw;     // b*64*16384
#pragma unroll
    for (int o = 0; o < 64; o++) v[vbase + o * 16384] = accv[o];
}

// ---------------------------------------------------------------------------
// Kernel 2: column direction. Block = (b, w).
// E_H[h][g] = exp(q[:,h,w].k[:,g,w]), 0 on diagonal.
// Writes sH[b,h,w] = sum_g E_H and unnormalized accH[c][h] into d_out.
// ---------------------------------------------------------------------------
__global__ __launch_bounds__(256) void colH_kernel(
    const float* __restrict__ q, const float* __restrict__ k,
    const float* __restrict__ v,
    float* __restrict__ accH, float* __restrict__ sH)
{
    __shared__ __align__(16) float qs[8 * 128];
    __shared__ __align__(16) float ks[8 * 128];
    __shared__ __align__(16) float Et[128 * PADE];   // Et[g][h]
    __shared__ __align__(16) float vs[128 * PADV];   // vs[g][c]

    int t = threadIdx.x;
    int bid = blockIdx.x;
    int wg = ((bid & 7) << 8) | (bid >> 3);   // XCD swizzle: batch-contiguous per XCD
    int b = wg >> 7, w = wg & 127;

    const float* qb = q + ((long)b << 17) + w;
    const float* kb = k + ((long)b << 17) + w;
#pragma unroll 4
    for (int i = t; i < 1024; i += 256) {
        int o = i >> 7, h = i & 127;
        qs[i] = qb[o * 16384 + h * 128];
        ks[i] = kb[o * 16384 + h * 128];
    }
    const float* vb = v + ((long)b << 20) + w;
#pragma unroll 8
    for (int i = t; i < 8192; i += 256) {
        int c = i >> 7, g = i & 127;
        vs[g * PADV + c] = vb[c * 16384 + g * 128];
    }
    __syncthreads();

#pragma unroll 4
    for (int i = t; i < 16384; i += 256) {
        int g = i >> 7, h = i & 127;
        float d = 0.f;
#pragma unroll
        for (int o = 0; o < 8; o++) d += qs[o * 128 + h] * ks[o * 128 + g];
        Et[g * PADE + h] = (g == h) ? 0.f : __expf(d);
    }
    __syncthreads();

    if (t < 128) {
        float s = 0.f;
        for (int g = 0; g < 128; g++) s += Et[g * PADE + t];
        sH[((long)b << 14) + t * 128 + w] = s;
    }

    // GEMM: acc[c][h] = sum_g Et[g][h] * vs[g][c]; thread owns 4 h x 8 c
    int hq = t & 31, cg = t >> 5;
    float acc[4][8];
#pragma unroll
    for (int j = 0; j < 4; j++)
#pragma unroll
        for (int i = 0; i < 8; i++) acc[j][i] = 0.f;

#pragma unroll 2
    for (int g = 0; g < 128; g++) {
        float4 e4 = *(const float4*)&Et[g * PADE + hq * 4];
        float4 va = *(const float4*)&vs[g * PADV + cg * 8];
        float4 vb4 = *(const float4*)&vs[g * PADV + cg * 8 + 4];
        float ev[4] = { e4.x, e4.y, e4.z, e4.w };
        float vv[8] = { va.x, va.y, va.z, va.w, vb4.x, vb4.y, vb4.z, vb4.w };
#pragma unroll
        for (int j = 0; j < 4; j++)
#pragma unroll
            for (int i = 0; i < 8; i++) acc[j][i] += ev[j] * vv[i];
    }

    long obase = ((long)b << 20) + w;
#pragma unroll
    for (int i = 0; i < 8; i++) {
        int c = cg * 8 + i;
#pragma unroll
        for (int j = 0; j < 4; j++) {
            int h = hq * 4 + j;
            accH[obase + c * 16384 + h * 128] = acc[j][i];
        }
    }
}

// ---------------------------------------------------------------------------
// Kernel 3: row direction + finalize. Block = (b, h).
// E_W[w][v] = exp(q[:,h,w].k[:,h,v]) (no mask).
// out = gamma*(accH + accW)/(sH + sW) + x
// ---------------------------------------------------------------------------
__global__ __launch_bounds__(256) void rowW_kernel(
    const float* __restrict__ q, const float* __restrict__ k,
    const float* __restrict__ v,
    const float* __restrict__ sH, const float* __restrict__ x,
    const float* __restrict__ gamma, float* __restrict__ out)
{
    __shared__ __align__(16) float qs[8 * 128];
    __shared__ __align__(16) float ks[8 * 128];
    __shared__ __align__(16) float Et[128 * PADE];   // Et[v][w]
    __shared__ __align__(16) float vs[128 * PADV];   // vs[v][c]
    __shared__ float stot[128];

    int t = threadIdx.x;
    int bid = blockIdx.x;
    int wg = ((bid & 7) << 8) | (bid >> 3);
    int b = wg >> 7, h = wg & 127;

    long rowoff = ((long)b << 17) + h * 128;
#pragma unroll 4
    for (int i = t; i < 1024; i += 256) {
        int o = i >> 7, w = i & 127;
        qs[i] = q[rowoff + o * 16384 + w];
        ks[i] = k[rowoff + o * 16384 + w];
    }
    long vrow = ((long)b << 20) + h * 128;
#pragma unroll 8
    for (int i = t; i < 8192; i += 256) {
        int c = i >> 7, vv = i & 127;
        vs[vv * PADV + c] = v[vrow + c * 16384 + vv];
    }
    __syncthreads();

#pragma unroll 4
    for (int i = t; i < 16384; i += 256) {
        int vv = i >> 7, w = i & 127;
        float d = 0.f;
#pragma unroll
        for (int o = 0; o < 8; o++) d += qs[o * 128 + w] * ks[o * 128 + vv];
        Et[vv * PADE + w] = __expf(d);
    }
    __syncthreads();

    if (t < 128) {
        float s = 0.f;
        for (int vv = 0; vv < 128; vv++) s += Et[vv * PADE + t];
        stot[t] = s + sH[((long)b << 14) + h * 128 + t];
    }
    __syncthreads();

    int wq = t & 31, cg = t >> 5;
    float acc[4][8];
#pragma unroll
    for (int j = 0; j < 4; j++)
#pragma unroll
        for (int i = 0; i < 8; i++) acc[j][i] = 0.f;

#pragma unroll 2
    for (int vv = 0; vv < 128; vv++) {
        float4 e4 = *(const float4*)&Et[vv * PADE + wq * 4];
        float4 va = *(const float4*)&vs[vv * PADV + cg * 8];
        float4 vb4 = *(const float4*)&vs[vv * PADV + cg * 8 + 4];
        float ev[4] = { e4.x, e4.y, e4.z, e4.w };
        float vvv[8] = { va.x, va.y, va.z, va.w, vb4.x, vb4.y, vb4.z, vb4.w };
#pragma unroll
        for (int j = 0; j < 4; j++)
#pragma unroll
            for (int i = 0; i < 8; i++) acc[j][i] += ev[j] * vvv[i];
    }

    float gm = gamma[0];
    float rs[4];
#pragma unroll
    for (int j = 0; j < 4; j++) rs[j] = 1.0f / stot[wq * 4 + j];

    long obase = ((long)b << 20) + h * 128 + wq * 4;
#pragma unroll
    for (int i = 0; i < 8; i++) {
        int c = cg * 8 + i;
        float4 ah = *(const float4*)&out[obase + c * 16384];
        float4 xv = *(const float4*)&x[obase + c * 16384];
        float4 r;
        r.x = gm * (ah.x + acc[0][i]) * rs[0] + xv.x;
        r.y = gm * (ah.y + acc[1][i]) * rs[1] + xv.y;
        r.z = gm * (ah.z + acc[2][i]) * rs[2] + xv.z;
        r.w = gm * (ah.w + acc[3][i]) * rs[3] + xv.w;
        *(float4*)&out[obase + c * 16384] = r;
    }
}

extern "C" void kernel_launch(void* const* d_in, const int* in_sizes, int n_in,
                              void* d_out, int out_size, void* d_ws, size_t ws_size,
                              hipStream_t stream) {
    const float* x     = (const float*)d_in[0];
    const float* Wq    = (const float*)d_in[1];
    const float* bq    = (const float*)d_in[2];
    const float* Wk    = (const float*)d_in[3];
    const float* bk    = (const float*)d_in[4];
    const float* Wv    = (const float*)d_in[5];
    const float* bv    = (const float*)d_in[6];
    const float* gamma = (const float*)d_in[7];
    float* out = (float*)d_out;

    float* ws = (float*)d_ws;
    float* q  = ws;                  // 16*8*128*128  = 2,097,152 floats
    float* k  = q + 2097152;         // 2,097,152
    float* v  = k + 2097152;         // 16*64*128*128 = 16,777,216
    float* sH = v + 16777216;        // 262,144
    // total ~85 MB of workspace

    proj_kernel<<<1024, 256, 0, stream>>>(x, Wq, bq, Wk, bk, Wv, bv, q, k, v);
    colH_kernel<<<2048, 256, 0, stream>>>(q, k, v, out, sH);
    rowW_kernel<<<2048, 256, 0, stream>>>(q, k, v, sH, x, gamma, out);
}

// Round 2
// 329.411 us; speedup vs baseline: 1.5302x; 1.5302x over previous
//
#include <hip/hip_runtime.h>
#include <hip/hip_bf16.h>

// Problem constants: B=16, C=64, CQ=8, H=W=128
#define PADE 132   // Et row stride (floats)
#define PADV 68    // v-tile row stride (floats)
#define TG   32    // g-tile size

// ---------------------------------------------------------------------------
// Kernel 1: projections q,k (C->8), v (C->64). One thread per pixel.
// ---------------------------------------------------------------------------
__global__ __launch_bounds__(256) void proj_kernel(
    const float* __restrict__ x,
    const float* __restrict__ Wq, const float* __restrict__ bq,
    const float* __restrict__ Wk, const float* __restrict__ bk,
    const float* __restrict__ Wv, const float* __restrict__ bv,
    float* __restrict__ q, float* __restrict__ k, float* __restrict__ v)
{
    __shared__ __align__(16) float sWv[64 * 64];
    __shared__ __align__(16) float sWq[8 * 64];
    __shared__ __align__(16) float sWk[8 * 64];
    __shared__ float sbias[80];

    int t = threadIdx.x;
    for (int i = t; i < 4096; i += 256) sWv[i] = Wv[i];
    for (int i = t; i < 512; i += 256) { sWq[i] = Wq[i]; sWk[i] = Wk[i]; }
    if (t < 64) sbias[t] = bv[t];
    else if (t < 72) sbias[t] = bq[t - 64];
    else if (t < 80) sbias[t] = bk[t - 72];
    __syncthreads();

    int pix = blockIdx.x * 256 + t;
    int b = pix >> 14;
    int hw = pix & 16383;
    const float* xp = x + ((long)b << 20) + hw;

    float accv[64], accq[8], acck[8];
#pragma unroll
    for (int o = 0; o < 64; o++) accv[o] = sbias[o];
#pragma unroll
    for (int o = 0; o < 8; o++) { accq[o] = sbias[64 + o]; acck[o] = sbias[72 + o]; }

    for (int c = 0; c < 64; c += 4) {
        float x0 = xp[(c + 0) * 16384];
        float x1 = xp[(c + 1) * 16384];
        float x2 = xp[(c + 2) * 16384];
        float x3 = xp[(c + 3) * 16384];
#pragma unroll
        for (int o = 0; o < 64; o++) {
            float4 wv = *(const float4*)&sWv[o * 64 + c];
            accv[o] += wv.x * x0 + wv.y * x1 + wv.z * x2 + wv.w * x3;
        }
#pragma unroll
        for (int o = 0; o < 8; o++) {
            float4 wq4 = *(const float4*)&sWq[o * 64 + c];
            accq[o] += wq4.x * x0 + wq4.y * x1 + wq4.z * x2 + wq4.w * x3;
            float4 wk4 = *(const float4*)&sWk[o * 64 + c];
            acck[o] += wk4.x * x0 + wk4.y * x1 + wk4.z * x2 + wk4.w * x3;
        }
    }

    long qbase = ((long)b << 17) + hw;
#pragma unroll
    for (int o = 0; o < 8; o++) {
        q[qbase + o * 16384] = accq[o];
        k[qbase + o * 16384] = acck[o];
    }
    long vbase = ((long)b << 20) + hw;
#pragma unroll
    for (int o = 0; o < 64; o++) v[vbase + o * 16384] = accv[o];
}

// ---------------------------------------------------------------------------
// Kernel 2: column direction. Block = (b, w), 512 threads, g tiled by 32,
// double-buffered Et / v tiles. Writes unnormalized accH into d_out, sH.
// ---------------------------------------------------------------------------
__global__ __launch_bounds__(512) void colH_kernel(
    const float* __restrict__ q, const float* __restrict__ k,
    const float* __restrict__ v,
    float* __restrict__ accH, float* __restrict__ sH)
{
    __shared__ __align__(16) float qs[8 * 128];
    __shared__ __align__(16) float ks[8 * 128];
    __shared__ __align__(16) float Et[2][TG][PADE];
    __shared__ __align__(16) float vt[2][TG][PADV];

    int t = threadIdx.x;
    int bid = blockIdx.x;
    int wg = ((bid & 7) << 8) | (bid >> 3);   // XCD swizzle (bijective, 2048=8*256)
    int b = wg >> 7, w = wg & 127;

    const float* qb = q + ((long)b << 17) + w;
    const float* kb = k + ((long)b << 17) + w;
#pragma unroll
    for (int i = t; i < 1024; i += 512) {
        int o = i >> 7, h = i & 127;
        qs[i] = qb[o * 16384 + h * 128];
        ks[i] = kb[o * 16384 + h * 128];
    }

    const float* vb = v + ((long)b << 20) + w;
    int sg = t & 31;        // g within tile
    int sc0 = t >> 5;       // c base (0..15), covers c = sc0 + 16u
    float rv[4];
    {
        const float* p = vb + sg * 128;   // tile 0: g0 = 0
#pragma unroll
        for (int u = 0; u < 4; u++) rv[u] = p[(sc0 + 16 * u) * 16384];
    }
    __syncthreads();

    // per-thread q fragment for E build
    int eh = t & 127, gl = t >> 7;        // gl 0..3
    float qv[8];
#pragma unroll
    for (int o = 0; o < 8; o++) qv[o] = qs[o * 128 + eh];

    // build Et[0] (tile 0) + commit vt[0]
#pragma unroll
    for (int j = 0; j < 8; j++) {
        int g = gl + 4 * j;               // tile-local == global for tile 0
        float d = 0.f;
#pragma unroll
        for (int o = 0; o < 8; o++) d += qv[o] * ks[o * 128 + g];
        Et[0][g][eh] = (g == eh) ? 0.f : __expf(d);
    }
#pragma unroll
    for (int u = 0; u < 4; u++) vt[0][sg][sc0 + 16 * u] = rv[u];
    __syncthreads();

    int hq = t & 31, cg = t >> 5;
    float acc[4][4];
#pragma unroll
    for (int j = 0; j < 4; j++)
#pragma unroll
        for (int i = 0; i < 4; i++) acc[j][i] = 0.f;
    float ssum[4] = {0.f, 0.f, 0.f, 0.f};

    for (int it = 0; it < 4; it++) {
        int buf = it & 1;
        if (it < 3) {
            int g0n = (it + 1) * TG;
            // issue next v-tile loads early
            const float* p = vb + (g0n + sg) * 128;
#pragma unroll
            for (int u = 0; u < 4; u++) rv[u] = p[(sc0 + 16 * u) * 16384];
            // build next Et tile (covers load latency)
#pragma unroll
            for (int j = 0; j < 8; j++) {
                int g = gl + 4 * j;
                int gg = g0n + g;
                float d = 0.f;
#pragma unroll
                for (int o = 0; o < 8; o++) d += qv[o] * ks[o * 128 + gg];
                Et[buf ^ 1][g][eh] = (gg == eh) ? 0.f : __expf(d);
            }
#pragma unroll
            for (int u = 0; u < 4; u++) vt[buf ^ 1][sg][sc0 + 16 * u] = rv[u];
        }
        // GEMM on current buffer
#pragma unroll 4
        for (int g = 0; g < TG; g++) {
            float4 e4 = *(const float4*)&Et[buf][g][hq * 4];
            float4 v4 = *(const float4*)&vt[buf][g][cg * 4];
            float ev[4] = { e4.x, e4.y, e4.z, e4.w };
            float vv[4] = { v4.x, v4.y, v4.z, v4.w };
#pragma unroll
            for (int j = 0; j < 4; j++)
#pragma unroll
                for (int i = 0; i < 4; i++) acc[j][i] += ev[j] * vv[i];
            if (cg == 0) {
#pragma unroll
                for (int j = 0; j < 4; j++) ssum[j] += ev[j];
            }
        }
        __syncthreads();
    }

    long obase = ((long)b << 20) + w;
#pragma unroll
    for (int i = 0; i < 4; i++) {
        int c = cg * 4 + i;
#pragma unroll
        for (int j = 0; j < 4; j++)
            accH[obase + c * 16384 + (hq * 4 + j) * 128] = acc[j][i];
    }
    if (cg == 0) {
        long sb = ((long)b << 14) + w;
#pragma unroll
        for (int j = 0; j < 4; j++) sH[sb + (hq * 4 + j) * 128] = ssum[j];
    }
}

// ---------------------------------------------------------------------------
// Kernel 3: row direction + finalize. Block = (b, h), same structure.
// out = gamma*(accH + accW)/(sH + sW) + x
// ---------------------------------------------------------------------------
__global__ __launch_bounds__(512) void rowW_kernel(
    const float* __restrict__ q, const float* __restrict__ k,
    const float* __restrict__ v,
    const float* __restrict__ sH, const float* __restrict__ x,
    const float* __restrict__ gamma, float* __restrict__ out)
{
    __shared__ __align__(16) float qs[8 * 128];
    __shared__ __align__(16) float ks[8 * 128];
    __shared__ __align__(16) float Et[2][TG][PADE];
    __shared__ __align__(16) float vt[2][TG][PADV];
    __shared__ float stot[128];

    int t = threadIdx.x;
    int bid = blockIdx.x;
    int wg = ((bid & 7) << 8) | (bid >> 3);
    int b = wg >> 7, h = wg & 127;

    long rowoff = ((long)b << 17) + h * 128;
#pragma unroll
    for (int i = t; i < 1024; i += 512) {
        int o = i >> 7, ww = i & 127;
        qs[i] = q[rowoff + o * 16384 + ww];
        ks[i] = k[rowoff + o * 16384 + ww];
    }

    long vrow = ((long)b << 20) + h * 128;
    int sg = t & 31;        // v-index within tile
    int sc0 = t >> 5;
    float rv[4];
    {
#pragma unroll
        for (int u = 0; u < 4; u++) rv[u] = v[vrow + (sc0 + 16 * u) * 16384 + sg];
    }
    __syncthreads();

    int ew = t & 127, gl = t >> 7;
    float qv[8];
#pragma unroll
    for (int o = 0; o < 8; o++) qv[o] = qs[o * 128 + ew];

#pragma unroll
    for (int j = 0; j < 8; j++) {
        int g = gl + 4 * j;
        float d = 0.f;
#pragma unroll
        for (int o = 0; o < 8; o++) d += qv[o] * ks[o * 128 + g];
        Et[0][g][ew] = __expf(d);     // no diagonal mask in W direction
    }
#pragma unroll
    for (int u = 0; u < 4; u++) vt[0][sg][sc0 + 16 * u] = rv[u];
    __syncthreads();

    int wq = t & 31, cg = t >> 5;
    float acc[4][4];
#pragma unroll
    for (int j = 0; j < 4; j++)
#pragma unroll
        for (int i = 0; i < 4; i++) acc[j][i] = 0.f;
    float ssum[4] = {0.f, 0.f, 0.f, 0.f};

    for (int it = 0; it < 4; it++) {
        int buf = it & 1;
        if (it < 3) {
            int g0n = (it + 1) * TG;
#pragma unroll
            for (int u = 0; u < 4; u++)
                rv[u] = v[vrow + (sc0 + 16 * u) * 16384 + g0n + sg];
#pragma unroll
            for (int j = 0; j < 8; j++) {
                int g = gl + 4 * j;
                int gg = g0n + g;
                float d = 0.f;
#pragma unroll
                for (int o = 0; o < 8; o++) d += qv[o] * ks[o * 128 + gg];
                Et[buf ^ 1][g][ew] = __expf(d);
            }
#pragma unroll
            for (int u = 0; u < 4; u++) vt[buf ^ 1][sg][sc0 + 16 * u] = rv[u];
        }
#pragma unroll 4
        for (int g = 0; g < TG; g++) {
            float4 e4 = *(const float4*)&Et[buf][g][wq * 4];
            float4 v4 = *(const float4*)&vt[buf][g][cg * 4];
            float ev[4] = { e4.x, e4.y, e4.z, e4.w };
            float vv[4] = { v4.x, v4.y, v4.z, v4.w };
#pragma unroll
            for (int j = 0; j < 4; j++)
#pragma unroll
                for (int i = 0; i < 4; i++) acc[j][i] += ev[j] * vv[i];
            if (cg == 0) {
#pragma unroll
                for (int j = 0; j < 4; j++) ssum[j] += ev[j];
            }
        }
        __syncthreads();
    }

    if (cg == 0) {
        long sb = ((long)b << 14) + h * 128;
#pragma unroll
        for (int j = 0; j < 4; j++)
            stot[wq * 4 + j] = ssum[j] + sH[sb + wq * 4 + j];
    }
    __syncthreads();

    float gm = gamma[0];
    float rs[4];
#pragma unroll
    for (int j = 0; j < 4; j++) rs[j] = 1.0f / stot[wq * 4 + j];

    long obase = ((long)b << 20) + h * 128 + wq * 4;
#pragma unroll
    for (int i = 0; i < 4; i++) {
        int c = cg * 4 + i;
        float4 ah = *(const float4*)&out[obase + c * 16384];
        float4 xv = *(const float4*)&x[obase + c * 16384];
        float4 r;
        r.x = gm * (ah.x + acc[0][i]) * rs[0] + xv.x;
        r.y = gm * (ah.y + acc[1][i]) * rs[1] + xv.y;
        r.z = gm * (ah.z + acc[2][i]) * rs[2] + xv.z;
        r.w = gm * (ah.w + acc[3][i]) * rs[3] + xv.w;
        *(float4*)&out[obase + c * 16384] = r;
    }
}

extern "C" void kernel_launch(void* const* d_in, const int* in_sizes, int n_in,
                              void* d_out, int out_size, void* d_ws, size_t ws_size,
                              hipStream_t stream) {
    const float* x     = (const float*)d_in[0];
    const float* Wq    = (const float*)d_in[1];
    const float* bq    = (const float*)d_in[2];
    const float* Wk    = (const float*)d_in[3];
    const float* bk    = (const float*)d_in[4];
    const float* Wv    = (const float*)d_in[5];
    const float* bv    = (const float*)d_in[6];
    const float* gamma = (const float*)d_in[7];
    float* out = (float*)d_out;

    float* ws = (float*)d_ws;
    float* q  = ws;                  // 2,097,152 floats
    float* k  = q + 2097152;         // 2,097,152
    float* v  = k + 2097152;         // 16,777,216
    float* sH = v + 16777216;        // 262,144

    proj_kernel<<<1024, 256, 0, stream>>>(x, Wq, bq, Wk, bk, Wv, bv, q, k, v);
    colH_kernel<<<2048, 512, 0, stream>>>(q, k, v, out, sH);
    rowW_kernel<<<2048, 512, 0, stream>>>(q, k, v, sH, x, gamma, out);
}

// Round 3
// 228.936 us; speedup vs baseline: 2.2018x; 1.4389x over previous
//
#include <hip/hip_runtime.h>
#include <hip/hip_bf16.h>

// B=16, C=64, CQ=8, H=W=128
typedef unsigned short u16;
typedef __attribute__((ext_vector_type(8))) short    bf16x8;
typedef __attribute__((ext_vector_type(8))) unsigned short us8;
typedef __attribute__((ext_vector_type(4))) unsigned short us4;
typedef __attribute__((ext_vector_type(4))) float    f32x4;
typedef __attribute__((ext_vector_type(2))) unsigned int u32x2;

__device__ __forceinline__ u16 f2bf(float f) {
    unsigned u = __float_as_uint(f);
    return (u16)((u + 0x7FFFu + ((u >> 16) & 1u)) >> 16);
}

// ---------------------------------------------------------------------------
// Kernel 1: projections. Writes bf16 v [b][c][h][w] and 4 packed q/k layouts:
// qTc/kTc: [b][w][h][8o]  (colH staging, 16B/slot),  qTr/kTr: [b][h][w][8o].
// ---------------------------------------------------------------------------
__global__ __launch_bounds__(256) void proj_kernel(
    const float* __restrict__ x,
    const float* __restrict__ Wq, const float* __restrict__ bq,
    const float* __restrict__ Wk, const float* __restrict__ bk,
    const float* __restrict__ Wv, const float* __restrict__ bv,
    u16* __restrict__ vb16,
    u16* __restrict__ qTc, u16* __restrict__ kTc,
    u16* __restrict__ qTr, u16* __restrict__ kTr)
{
    __shared__ __align__(16) float sWv[64 * 64];
    __shared__ __align__(16) float sWq[8 * 64];
    __shared__ __align__(16) float sWk[8 * 64];
    __shared__ float sbias[80];

    int t = threadIdx.x;
    for (int i = t; i < 4096; i += 256) sWv[i] = Wv[i];
    for (int i = t; i < 512; i += 256) { sWq[i] = Wq[i]; sWk[i] = Wk[i]; }
    if (t < 64) sbias[t] = bv[t];
    else if (t < 72) sbias[t] = bq[t - 64];
    else if (t < 80) sbias[t] = bk[t - 72];
    __syncthreads();

    int pix = blockIdx.x * 256 + t;
    int b = pix >> 14;
    int hw = pix & 16383;
    const float* xp = x + ((long)b << 20) + hw;

    float accv[64], accq[8], acck[8];
#pragma unroll
    for (int o = 0; o < 64; o++) accv[o] = sbias[o];
#pragma unroll
    for (int o = 0; o < 8; o++) { accq[o] = sbias[64 + o]; acck[o] = sbias[72 + o]; }

    for (int c = 0; c < 64; c += 4) {
        float x0 = xp[(c + 0) * 16384];
        float x1 = xp[(c + 1) * 16384];
        float x2 = xp[(c + 2) * 16384];
        float x3 = xp[(c + 3) * 16384];
#pragma unroll
        for (int o = 0; o < 64; o++) {
            float4 wv = *(const float4*)&sWv[o * 64 + c];
            accv[o] += wv.x * x0 + wv.y * x1 + wv.z * x2 + wv.w * x3;
        }
#pragma unroll
        for (int o = 0; o < 8; o++) {
            float4 wq4 = *(const float4*)&sWq[o * 64 + c];
            accq[o] += wq4.x * x0 + wq4.y * x1 + wq4.z * x2 + wq4.w * x3;
            float4 wk4 = *(const float4*)&sWk[o * 64 + c];
            acck[o] += wk4.x * x0 + wk4.y * x1 + wk4.z * x2 + wk4.w * x3;
        }
    }

    int h = hw >> 7, w = hw & 127;
    int vbase = (b << 20) + hw;
#pragma unroll
    for (int c = 0; c < 64; c++) vb16[vbase + (c << 14)] = f2bf(accv[c]);

    us8 pq, pk;
#pragma unroll
    for (int o = 0; o < 8; o++) { pq[o] = f2bf(accq[o]); pk[o] = f2bf(acck[o]); }
    *(us8*)&qTr[((b << 14) + hw) * 8] = pq;
    *(us8*)&kTr[((b << 14) + hw) * 8] = pk;
    *(us8*)&qTc[((b << 14) + w * 128 + h) * 8] = pq;
    *(us8*)&kTc[((b << 14) + w * 128 + h) * 8] = pk;
}

// ---------------------------------------------------------------------------
// Kernel 2: v transpose: vb16[b][c][g][w] -> vTc[b][w][c][g] (bf16).
// ---------------------------------------------------------------------------
__global__ __launch_bounds__(256) void vtrans_kernel(
    const u16* __restrict__ vb16, u16* __restrict__ vTc)
{
    __shared__ u16 tile[32][33];
    int t = threadIdx.x;
    int bid = blockIdx.x;
    int b = bid >> 10;
    int c = (bid >> 4) & 63;
    int g0 = ((bid >> 2) & 3) * 32, w0 = (bid & 3) * 32;
    const u16* src = vb16 + ((b * 64 + c) << 14);
#pragma unroll
    for (int it = 0; it < 4; it++) {
        int i = it * 8 + (t >> 5), j = t & 31;
        tile[i][j] = src[(g0 + i) * 128 + w0 + j];
    }
    __syncthreads();
    int j = t >> 3, i4 = (t & 7) * 4;
    us4 o = { tile[i4][j], tile[i4 + 1][j], tile[i4 + 2][j], tile[i4 + 3][j] };
    *(us4*)&vTc[((b * 128 + w0 + j) * 64 + c) * 128 + g0 + i4] = o;
}

// ---------------------------------------------------------------------------
// Kernel 3: column attention (MFMA). Block = (b,w), 512 thr = 8 waves.
// E = exp(K^T Q) masked; PV with ones-column -> unnorm accH (f32, in d_out)
// and sH[b][h][w].
// MFMA 16x16x32_bf16 layouts: A lane l: A[l&15][(l>>4)*8+j]; B: B[(l>>4)*8+j][l&15];
// D: row=(l>>4)*4+r, col=l&15.
// ---------------------------------------------------------------------------
__global__ __launch_bounds__(512) void colH_kernel(
    const u16* __restrict__ qTc, const u16* __restrict__ kTc,
    const u16* __restrict__ vTc,
    float* __restrict__ accH, float* __restrict__ sH)
{
    __shared__ u16 Qpk[129 * 8];       // slot 128 = zeros (K-dim pad)
    __shared__ u16 Kpk[129 * 8];
    __shared__ u16 Epk[2048 * 8];      // A-frag slots: [mt(8)][kt(4)][lane(64)][8]
    __shared__ u16 Vpk[1280 * 8];      // B-frag slots: [nt(5)][kt(4)][lane(64)][8]

    int t = threadIdx.x;
    int bid = blockIdx.x;
    int wg = ((bid & 7) << 8) | (bid >> 3);
    int b = wg >> 7, w = wg & 127;

    const u16* qB = qTc + ((b << 14) + w * 128) * 8;
    const u16* kB = kTc + ((b << 14) + w * 128) * 8;
    if (t < 128)      *(us8*)&Qpk[t * 8] = *(const us8*)&qB[t * 8];
    else if (t == 128) { us8 z = {0,0,0,0,0,0,0,0}; *(us8*)&Qpk[128 * 8] = z; }
    else if (t >= 256 && t < 384) *(us8*)&Kpk[(t - 256) * 8] = *(const us8*)&kB[(t - 256) * 8];
    else if (t == 384) { us8 z = {0,0,0,0,0,0,0,0}; *(us8*)&Kpk[128 * 8] = z; }

    const u16* vB = vTc + ((long)(b * 128 + w) << 13);
    for (int ss = 0; ss < 3; ss++) {
        int s = t + ss * 512;
        if (s < 1280) {
            int nt = s >> 8, kt = (s >> 6) & 3, sl = s & 63;
            us8 val;
            if (nt < 4) {
                int c = nt * 16 + (sl & 15), g = kt * 32 + ((sl >> 4) << 3);
                val = *(const us8*)&vB[c * 128 + g];
            } else {
                us8 z = {0,0,0,0,0,0,0,0};
                val = z;
                if ((sl & 15) == 0) {
#pragma unroll
                    for (int j = 0; j < 8; j++) val[j] = 0x3F80;  // bf16 1.0
                }
            }
            *(us8*)&Vpk[s * 8] = val;
        }
    }
    __syncthreads();

    int wv = t >> 6, l = t & 63;
    int m16 = l & 15, kg = l >> 4;
    f32x4 zero4 = {0.f, 0.f, 0.f, 0.f};

    // ---- QK^T: wave wv owns g-tile gt=wv; Et[g][h], rows g, cols h ----
    int gt = wv;
    bf16x8 afr;
    { int sl = (kg == 0) ? (gt * 16 + m16) : 128;
      afr = *(const bf16x8*)&Kpk[sl * 8]; }
    int kgr = ((gt & 1) << 1) | (kg >> 1);
    int jb  = (kg & 1) << 2;
    int gbase = gt * 16 + kg * 4;
#pragma unroll
    for (int ht = 0; ht < 8; ht++) {
        int slB = (kg == 0) ? (ht * 16 + m16) : 128;
        bf16x8 bfr = *(const bf16x8*)&Qpk[slB * 8];
        f32x4 e = __builtin_amdgcn_mfma_f32_16x16x32_bf16(afr, bfr, zero4, 0, 0, 0);
        u16 u0[4];
#pragma unroll
        for (int r = 0; r < 4; r++) {
            int g = gbase + r, h = ht * 16 + m16;
            float val = (g == h) ? 0.f : __expf(e[r]);
            u0[r] = f2bf(val);
        }
        int eidx = ((((ht << 2) | (gt >> 1)) * 64 + kgr * 16 + m16) << 3) + jb;
        u32x2 pk2;
        pk2.x = (unsigned)u0[0] | ((unsigned)u0[1] << 16);
        pk2.y = (unsigned)u0[2] | ((unsigned)u0[3] << 16);
        *(u32x2*)&Epk[eidx] = pk2;
    }
    __syncthreads();

    // ---- PV: wave wv owns h-tile mt=wv; D[h][c], c 0..63 + sum col 64 ----
    int mt = wv;
    bf16x8 a0 = *(const bf16x8*)&Epk[(((mt << 2) + 0) * 64 + l) << 3];
    bf16x8 a1 = *(const bf16x8*)&Epk[(((mt << 2) + 1) * 64 + l) << 3];
    bf16x8 a2 = *(const bf16x8*)&Epk[(((mt << 2) + 2) * 64 + l) << 3];
    bf16x8 a3 = *(const bf16x8*)&Epk[(((mt << 2) + 3) * 64 + l) << 3];
    f32x4 acc[5];
#pragma unroll
    for (int nt = 0; nt < 5; nt++) {
        f32x4 a_ = zero4;
        a_ = __builtin_amdgcn_mfma_f32_16x16x32_bf16(a0, *(const bf16x8*)&Vpk[(((nt << 2) + 0) * 64 + l) << 3], a_, 0, 0, 0);
        a_ = __builtin_amdgcn_mfma_f32_16x16x32_bf16(a1, *(const bf16x8*)&Vpk[(((nt << 2) + 1) * 64 + l) << 3], a_, 0, 0, 0);
        a_ = __builtin_amdgcn_mfma_f32_16x16x32_bf16(a2, *(const bf16x8*)&Vpk[(((nt << 2) + 2) * 64 + l) << 3], a_, 0, 0, 0);
        a_ = __builtin_amdgcn_mfma_f32_16x16x32_bf16(a3, *(const bf16x8*)&Vpk[(((nt << 2) + 3) * 64 + l) << 3], a_, 0, 0, 0);
        acc[nt] = a_;
    }

    // epilogue: scattered 4B writes (L2-combined; proven round 2)
    int obase = (b << 20) + w;
#pragma unroll
    for (int nt = 0; nt < 4; nt++) {
        int c = nt * 16 + m16;
#pragma unroll
        for (int r = 0; r < 4; r++) {
            int h = mt * 16 + kg * 4 + r;
            accH[obase + (c << 14) + (h << 7)] = acc[nt][r];
        }
    }
    if (m16 == 0) {
#pragma unroll
        for (int r = 0; r < 4; r++) {
            int h = mt * 16 + kg * 4 + r;
            sH[(b << 14) + (h << 7) + w] = acc[4][r];
        }
    }
}

// ---------------------------------------------------------------------------
// Kernel 4: row attention (MFMA) + finalize.
// out = gamma*(accH + accW)/(sH + sW) + x, coalesced via LDS out-stage.
// ---------------------------------------------------------------------------
__global__ __launch_bounds__(512) void rowW_kernel(
    const u16* __restrict__ qTr, const u16* __restrict__ kTr,
    const u16* __restrict__ vb16,
    const float* __restrict__ sH, const float* __restrict__ x,
    const float* __restrict__ gamma, float* __restrict__ out)
{
    __shared__ u16 Qpk[129 * 8];
    __shared__ u16 Kpk[129 * 8];
    __shared__ union UU {
        struct { u16 Epk[2048 * 8]; u16 Vpk[1280 * 8]; } s;
        float outS[64 * 132];
    } uu;
    __shared__ float stotS[128];

    int t = threadIdx.x;
    int bid = blockIdx.x;
    int wg = ((bid & 7) << 8) | (bid >> 3);
    int b = wg >> 7, h = wg & 127;

    const u16* qB = qTr + ((b << 14) + h * 128) * 8;
    const u16* kB = kTr + ((b << 14) + h * 128) * 8;
    if (t < 128)      *(us8*)&Qpk[t * 8] = *(const us8*)&qB[t * 8];
    else if (t == 128) { us8 z = {0,0,0,0,0,0,0,0}; *(us8*)&Qpk[128 * 8] = z; }
    else if (t >= 256 && t < 384) *(us8*)&Kpk[(t - 256) * 8] = *(const us8*)&kB[(t - 256) * 8];
    else if (t == 384) { us8 z = {0,0,0,0,0,0,0,0}; *(us8*)&Kpk[128 * 8] = z; }

    for (int ss = 0; ss < 3; ss++) {
        int s = t + ss * 512;
        if (s < 1280) {
            int nt = s >> 8, kt = (s >> 6) & 3, sl = s & 63;
            us8 val;
            if (nt < 4) {
                int c = nt * 16 + (sl & 15), g = kt * 32 + ((sl >> 4) << 3);
                val = *(const us8*)&vb16[(b << 20) + (c << 14) + (h << 7) + g];
            } else {
                us8 z = {0,0,0,0,0,0,0,0};
                val = z;
                if ((sl & 15) == 0) {
#pragma unroll
                    for (int j = 0; j < 8; j++) val[j] = 0x3F80;
                }
            }
            *(us8*)&uu.s.Vpk[s * 8] = val;
        }
    }
    __syncthreads();

    int wv = t >> 6, l = t & 63;
    int m16 = l & 15, kg = l >> 4;
    f32x4 zero4 = {0.f, 0.f, 0.f, 0.f};

    // ---- QK^T (no diagonal mask in W direction) ----
    int gt = wv;
    bf16x8 afr;
    { int sl = (kg == 0) ? (gt * 16 + m16) : 128;
      afr = *(const bf16x8*)&Kpk[sl * 8]; }
    int kgr = ((gt & 1) << 1) | (kg >> 1);
    int jb  = (kg & 1) << 2;
#pragma unroll
    for (int ht = 0; ht < 8; ht++) {
        int slB = (kg == 0) ? (ht * 16 + m16) : 128;
        bf16x8 bfr = *(const bf16x8*)&Qpk[slB * 8];
        f32x4 e = __builtin_amdgcn_mfma_f32_16x16x32_bf16(afr, bfr, zero4, 0, 0, 0);
        u16 u0[4];
#pragma unroll
        for (int r = 0; r < 4; r++) u0[r] = f2bf(__expf(e[r]));
        int eidx = ((((ht << 2) | (gt >> 1)) * 64 + kgr * 16 + m16) << 3) + jb;
        u32x2 pk2;
        pk2.x = (unsigned)u0[0] | ((unsigned)u0[1] << 16);
        pk2.y = (unsigned)u0[2] | ((unsigned)u0[3] << 16);
        *(u32x2*)&uu.s.Epk[eidx] = pk2;
    }
    __syncthreads();

    // ---- PV ----
    int mt = wv;
    bf16x8 a0 = *(const bf16x8*)&uu.s.Epk[(((mt << 2) + 0) * 64 + l) << 3];
    bf16x8 a1 = *(const bf16x8*)&uu.s.Epk[(((mt << 2) + 1) * 64 + l) << 3];
    bf16x8 a2 = *(const bf16x8*)&uu.s.Epk[(((mt << 2) + 2) * 64 + l) << 3];
    bf16x8 a3 = *(const bf16x8*)&uu.s.Epk[(((mt << 2) + 3) * 64 + l) << 3];
    f32x4 acc[5];
#pragma unroll
    for (int nt = 0; nt < 5; nt++) {
        f32x4 a_ = zero4;
        a_ = __builtin_amdgcn_mfma_f32_16x16x32_bf16(a0, *(const bf16x8*)&uu.s.Vpk[(((nt << 2) + 0) * 64 + l) << 3], a_, 0, 0, 0);
        a_ = __builtin_amdgcn_mfma_f32_16x16x32_bf16(a1, *(const bf16x8*)&uu.s.Vpk[(((nt << 2) + 1) * 64 + l) << 3], a_, 0, 0, 0);
        a_ = __builtin_amdgcn_mfma_f32_16x16x32_bf16(a2, *(const bf16x8*)&uu.s.Vpk[(((nt << 2) + 2) * 64 + l) << 3], a_, 0, 0, 0);
        a_ = __builtin_amdgcn_mfma_f32_16x16x32_bf16(a3, *(const bf16x8*)&uu.s.Vpk[(((nt << 2) + 3) * 64 + l) << 3], a_, 0, 0, 0);
        acc[nt] = a_;
    }
    __syncthreads();   // all PV reads of Epk/Vpk done before outS aliases them

    if (m16 == 0) {
#pragma unroll
        for (int r = 0; r < 4; r++) {
            int w_ = mt * 16 + kg * 4 + r;
            float s = acc[4][r] + sH[(b << 14) + (h << 7) + w_];
            stotS[w_] = 1.0f / s;
        }
    }
#pragma unroll
    for (int nt = 0; nt < 4; nt++) {
        int c = nt * 16 + m16;
#pragma unroll
        for (int r = 0; r < 4; r++)
            uu.outS[c * 132 + mt * 16 + kg * 4 + r] = acc[nt][r];
    }
    __syncthreads();

    float gm = gamma[0];
    int rbase = (b << 20) + (h << 7);
#pragma unroll
    for (int qq = 0; qq < 4; qq++) {
        int q_ = t + qq * 512;
        int c = q_ >> 5, w4 = (q_ & 31) << 2;
        int gaddr = rbase + (c << 14) + w4;
        float4 aW = *(float4*)&uu.outS[c * 132 + w4];
        float4 aH = *(const float4*)&out[gaddr];
        float4 xv = *(const float4*)&x[gaddr];
        float4 rs = *(float4*)&stotS[w4];
        float4 r;
        r.x = gm * (aH.x + aW.x) * rs.x + xv.x;
        r.y = gm * (aH.y + aW.y) * rs.y + xv.y;
        r.z = gm * (aH.z + aW.z) * rs.z + xv.z;
        r.w = gm * (aH.w + aW.w) * rs.w + xv.w;
        *(float4*)&out[gaddr] = r;
    }
}

extern "C" void kernel_launch(void* const* d_in, const int* in_sizes, int n_in,
                              void* d_out, int out_size, void* d_ws, size_t ws_size,
                              hipStream_t stream) {
    const float* x     = (const float*)d_in[0];
    const float* Wq    = (const float*)d_in[1];
    const float* bq    = (const float*)d_in[2];
    const float* Wk    = (const float*)d_in[3];
    const float* bk    = (const float*)d_in[4];
    const float* Wv    = (const float*)d_in[5];
    const float* bv    = (const float*)d_in[6];
    const float* gamma = (const float*)d_in[7];
    float* out = (float*)d_out;

    u16* vb16 = (u16*)d_ws;              // 16,777,216 u16 (32MB)
    u16* vTc  = vb16 + 16777216;         // 16,777,216 u16
    u16* qTc  = vTc + 16777216;          // 2,097,152 u16 each
    u16* kTc  = qTc + 2097152;
    u16* qTr  = kTc + 2097152;
    u16* kTr  = qTr + 2097152;
    float* sH = (float*)(kTr + 2097152); // 262,144 f32
    // total ~85 MB

    proj_kernel<<<1024, 256, 0, stream>>>(x, Wq, bq, Wk, bk, Wv, bv,
                                          vb16, qTc, kTc, qTr, kTr);
    vtrans_kernel<<<16384, 256, 0, stream>>>(vb16, vTc);
    colH_kernel<<<2048, 512, 0, stream>>>(qTc, kTc, vTc, out, sH);
    rowW_kernel<<<2048, 512, 0, stream>>>(qTr, kTr, vb16, sH, x, gamma, out);
}

// Round 4
// 171.460 us; speedup vs baseline: 2.9399x; 1.3352x over previous
//
#include <hip/hip_runtime.h>
#include <hip/hip_bf16.h>

// B=16, C=64, CQ=8, H=W=128
typedef unsigned short u16;
typedef __attribute__((ext_vector_type(8))) short    bf16x8;
typedef __attribute__((ext_vector_type(8))) unsigned short us8;
typedef __attribute__((ext_vector_type(4))) unsigned short us4;
typedef __attribute__((ext_vector_type(4))) float    f32x4;
typedef __attribute__((ext_vector_type(2))) unsigned int u32x2;

__device__ __forceinline__ u16 f2bf(float f) {
    unsigned u = __float_as_uint(f);
    return (u16)((u + 0x7FFFu + ((u >> 16) & 1u)) >> 16);
}

// ---------------------------------------------------------------------------
// Kernel 1: projections. Writes bf16 v [b][c][h][w] and packed qk:
// qkTr[b][h][w][16] = {q[8], k[8]}.
// ---------------------------------------------------------------------------
__global__ __launch_bounds__(256) void proj_kernel(
    const float* __restrict__ x,
    const float* __restrict__ Wq, const float* __restrict__ bq,
    const float* __restrict__ Wk, const float* __restrict__ bk,
    const float* __restrict__ Wv, const float* __restrict__ bv,
    u16* __restrict__ vb16, u16* __restrict__ qkTr)
{
    __shared__ __align__(16) float sWv[64 * 64];
    __shared__ __align__(16) float sWq[8 * 64];
    __shared__ __align__(16) float sWk[8 * 64];
    __shared__ float sbias[80];

    int t = threadIdx.x;
    for (int i = t; i < 4096; i += 256) sWv[i] = Wv[i];
    for (int i = t; i < 512; i += 256) { sWq[i] = Wq[i]; sWk[i] = Wk[i]; }
    if (t < 64) sbias[t] = bv[t];
    else if (t < 72) sbias[t] = bq[t - 64];
    else if (t < 80) sbias[t] = bk[t - 72];
    __syncthreads();

    int bid = blockIdx.x;
    int wg = ((bid & 7) << 7) | (bid >> 3);   // b-matched XCD swizzle
    int pix = wg * 256 + t;
    int b = pix >> 14;
    int hw = pix & 16383;
    const float* xp = x + ((long)b << 20) + hw;

    float accv[64], accq[8], acck[8];
#pragma unroll
    for (int o = 0; o < 64; o++) accv[o] = sbias[o];
#pragma unroll
    for (int o = 0; o < 8; o++) { accq[o] = sbias[64 + o]; acck[o] = sbias[72 + o]; }

    for (int c = 0; c < 64; c += 4) {
        float x0 = xp[(c + 0) * 16384];
        float x1 = xp[(c + 1) * 16384];
        float x2 = xp[(c + 2) * 16384];
        float x3 = xp[(c + 3) * 16384];
#pragma unroll
        for (int o = 0; o < 64; o++) {
            float4 wv = *(const float4*)&sWv[o * 64 + c];
            accv[o] += wv.x * x0 + wv.y * x1 + wv.z * x2 + wv.w * x3;
        }
#pragma unroll
        for (int o = 0; o < 8; o++) {
            float4 wq4 = *(const float4*)&sWq[o * 64 + c];
            accq[o] += wq4.x * x0 + wq4.y * x1 + wq4.z * x2 + wq4.w * x3;
            float4 wk4 = *(const float4*)&sWk[o * 64 + c];
            acck[o] += wk4.x * x0 + wk4.y * x1 + wk4.z * x2 + wk4.w * x3;
        }
    }

    int vbase = (b << 20) + hw;
#pragma unroll
    for (int c = 0; c < 64; c++) vb16[vbase + (c << 14)] = f2bf(accv[c]);

    us8 pq, pk;
#pragma unroll
    for (int o = 0; o < 8; o++) { pq[o] = f2bf(accq[o]); pk[o] = f2bf(acck[o]); }
    long qb = ((long)((b << 14) + hw)) << 4;
    *(us8*)&qkTr[qb] = pq;
    *(us8*)&qkTr[qb + 8] = pk;
}

// ---------------------------------------------------------------------------
// Kernel 2: v transpose: vb16[b][c][g][w] -> vTc[b][w][c][g] (bf16).
// ---------------------------------------------------------------------------
__global__ __launch_bounds__(256) void vtrans_kernel(
    const u16* __restrict__ vb16, u16* __restrict__ vTc)
{
    __shared__ u16 tile[32][33];
    int t = threadIdx.x;
    int bid = blockIdx.x;
    int vwg = ((bid & 7) << 11) | (bid >> 3);  // b-matched XCD swizzle
    int b = vwg >> 10;
    int c = (vwg >> 4) & 63;
    int g0 = ((vwg >> 2) & 3) * 32, w0 = (vwg & 3) * 32;
    const u16* src = vb16 + ((b * 64 + c) << 14);
#pragma unroll
    for (int it = 0; it < 4; it++) {
        int i = it * 8 + (t >> 5), j = t & 31;
        tile[i][j] = src[(g0 + i) * 128 + w0 + j];
    }
    __syncthreads();
    int j = t >> 3, i4 = (t & 7) * 4;
    us4 o = { tile[i4][j], tile[i4 + 1][j], tile[i4 + 2][j], tile[i4 + 3][j] };
    *(us4*)&vTc[((b * 128 + w0 + j) * 64 + c) * 128 + g0 + i4] = o;
}

// ---------------------------------------------------------------------------
// Kernel 3: column attention. Block (b,w), 512 thr = 8 waves.
// QK^T -> exp (diag masked) -> Epk (B-frag slots); PV = V^T(A) x E(B):
// D[c][h]. Writes accHt[b][w][h][c] bf16 (coalesced us4) + sH[b][w][h].
// ---------------------------------------------------------------------------
__global__ __launch_bounds__(512) void colH_kernel(
    const u16* __restrict__ qkTr, const u16* __restrict__ vTc,
    u16* __restrict__ accHt, float* __restrict__ sH)
{
    __shared__ u16 Qpk[129 * 8];       // slot 128 = zeros (K-dim pad)
    __shared__ u16 Kpk[129 * 8];
    __shared__ u16 Epk[2048 * 8];      // E B-frag slots [ht(8)][kt(4)][lane][8]
    __shared__ u16 Vs[1024 * 8];       // V^T tile [64c][16 slots][8], XOR-swizzled

    int t = threadIdx.x;
    int bid = blockIdx.x;
    int wg = ((bid & 7) << 8) | (bid >> 3);
    int b = wg >> 7, w = wg & 127;

    if (t < 128) {
        const u16* p = qkTr + (((long)((b << 14) + t * 128 + w)) << 4);
        *(us8*)&Qpk[t * 8] = *(const us8*)p;
        *(us8*)&Kpk[t * 8] = *(const us8*)(p + 8);
    } else if (t == 128) {
        us8 z = {0,0,0,0,0,0,0,0};
        *(us8*)&Qpk[128 * 8] = z;
        *(us8*)&Kpk[128 * 8] = z;
    }

    // stage V^T tile: LDS linear, source chunk index XOR-swizzled
    const u16* vB = vTc + ((long)(b * 128 + w) << 13);
#pragma unroll
    for (int m = t; m < 1024; m += 512) {
        int c = m >> 4, s = m & 15;
        int src = (c << 4) | (s & 8) | ((s ^ c) & 7);
        *(us8*)&Vs[m << 3] = *(const us8*)&vB[src << 3];
    }
    __syncthreads();

    int wv = t >> 6, l = t & 63;
    int m16 = l & 15, kg = l >> 4;
    f32x4 zero4 = {0.f, 0.f, 0.f, 0.f};

    // ---- QK^T: wave owns g-tile gt=wv; E[g][h] ----
    int gt = wv;
    bf16x8 afr;
    { int sl = (kg == 0) ? (gt * 16 + m16) : 128;
      afr = *(const bf16x8*)&Kpk[sl * 8]; }
    int kgr = ((gt & 1) << 1) | (kg >> 1);
    int jb  = (kg & 1) << 2;
    int gbase = gt * 16 + kg * 4;
#pragma unroll
    for (int ht = 0; ht < 8; ht++) {
        int slB = (kg == 0) ? (ht * 16 + m16) : 128;
        bf16x8 bfr = *(const bf16x8*)&Qpk[slB * 8];
        f32x4 e = __builtin_amdgcn_mfma_f32_16x16x32_bf16(afr, bfr, zero4, 0, 0, 0);
        u16 u0[4];
#pragma unroll
        for (int r = 0; r < 4; r++) {
            int g = gbase + r, h = ht * 16 + m16;
            float val = (g == h) ? 0.f : __expf(e[r]);
            u0[r] = f2bf(val);
        }
        int eidx = ((((ht << 2) | (gt >> 1)) * 64 + kgr * 16 + m16) << 3) + jb;
        u32x2 pk2;
        pk2.x = (unsigned)u0[0] | ((unsigned)u0[1] << 16);
        pk2.y = (unsigned)u0[2] | ((unsigned)u0[3] << 16);
        *(u32x2*)&Epk[eidx] = pk2;
    }
    __syncthreads();

    // ---- PV: D[c][h] = V^T x E. wave owns h-tile mt=wv ----
    int mt = wv;
    bf16x8 bE[4];
#pragma unroll
    for (int kt = 0; kt < 4; kt++)
        bE[kt] = *(const bf16x8*)&Epk[(((mt << 2) + kt) * 64 + l) << 3];

    bf16x8 ones;
    short ov = (m16 == 0) ? (short)0x3F80 : (short)0;
#pragma unroll
    for (int j = 0; j < 8; j++) ones[j] = ov;

    f32x4 acc[5];
#pragma unroll
    for (int i = 0; i < 5; i++) acc[i] = zero4;

#pragma unroll
    for (int ct = 0; ct < 4; ct++) {
#pragma unroll
        for (int kt = 0; kt < 4; kt++) {
            int slot = ((ct * 16 + m16) << 4) | ((((kt << 2) | kg)) ^ (m16 & 7));
            bf16x8 aV = *(const bf16x8*)&Vs[slot << 3];
            acc[ct] = __builtin_amdgcn_mfma_f32_16x16x32_bf16(aV, bE[kt], acc[ct], 0, 0, 0);
        }
    }
#pragma unroll
    for (int kt = 0; kt < 4; kt++)
        acc[4] = __builtin_amdgcn_mfma_f32_16x16x32_bf16(ones, bE[kt], acc[4], 0, 0, 0);

    // epilogue: accHt[b][w][h][c] bf16 (8B-coalesced), sH[b][w][h]
    long obase = (((long)(b * 128 + w)) * 128 + mt * 16 + m16) * 64;
#pragma unroll
    for (int ct = 0; ct < 4; ct++) {
        us4 pkd = { f2bf(acc[ct][0]), f2bf(acc[ct][1]), f2bf(acc[ct][2]), f2bf(acc[ct][3]) };
        *(us4*)&accHt[obase + ct * 16 + kg * 4] = pkd;
    }
    if (kg == 0)
        sH[(b * 128 + w) * 128 + mt * 16 + m16] = acc[4][0];
}

// ---------------------------------------------------------------------------
// Kernel 4: row attention (mirror). Writes accWt[b][h][w][c] bf16 + sW[b][h][w].
// ---------------------------------------------------------------------------
__global__ __launch_bounds__(512) void rowW_kernel(
    const u16* __restrict__ qkTr, const u16* __restrict__ vb16,
    u16* __restrict__ accWt, float* __restrict__ sW)
{
    __shared__ u16 Qpk[129 * 8];
    __shared__ u16 Kpk[129 * 8];
    __shared__ u16 Epk[2048 * 8];
    __shared__ u16 Vs[1024 * 8];

    int t = threadIdx.x;
    int bid = blockIdx.x;
    int wg = ((bid & 7) << 8) | (bid >> 3);
    int b = wg >> 7, h = wg & 127;

    if (t < 128) {
        const u16* p = qkTr + (((long)((b << 14) + h * 128 + t)) << 4);
        *(us8*)&Qpk[t * 8] = *(const us8*)p;
        *(us8*)&Kpk[t * 8] = *(const us8*)(p + 8);
    } else if (t == 128) {
        us8 z = {0,0,0,0,0,0,0,0};
        *(us8*)&Qpk[128 * 8] = z;
        *(us8*)&Kpk[128 * 8] = z;
    }

    const u16* vB = vb16 + ((long)b << 20) + (h << 7);
#pragma unroll
    for (int m = t; m < 1024; m += 512) {
        int c = m >> 4, s = m & 15;
        int src = (s & 8) | ((s ^ c) & 7);
        *(us8*)&Vs[m << 3] = *(const us8*)&vB[((long)c << 14) + (src << 3)];
    }
    __syncthreads();

    int wv = t >> 6, l = t & 63;
    int m16 = l & 15, kg = l >> 4;
    f32x4 zero4 = {0.f, 0.f, 0.f, 0.f};

    // ---- QK^T: E[v][w], no diagonal mask ----
    int gt = wv;
    bf16x8 afr;
    { int sl = (kg == 0) ? (gt * 16 + m16) : 128;
      afr = *(const bf16x8*)&Kpk[sl * 8]; }
    int kgr = ((gt & 1) << 1) | (kg >> 1);
    int jb  = (kg & 1) << 2;
#pragma unroll
    for (int ht = 0; ht < 8; ht++) {
        int slB = (kg == 0) ? (ht * 16 + m16) : 128;
        bf16x8 bfr = *(const bf16x8*)&Qpk[slB * 8];
        f32x4 e = __builtin_amdgcn_mfma_f32_16x16x32_bf16(afr, bfr, zero4, 0, 0, 0);
        u16 u0[4];
#pragma unroll
        for (int r = 0; r < 4; r++) u0[r] = f2bf(__expf(e[r]));
        int eidx = ((((ht << 2) | (gt >> 1)) * 64 + kgr * 16 + m16) << 3) + jb;
        u32x2 pk2;
        pk2.x = (unsigned)u0[0] | ((unsigned)u0[1] << 16);
        pk2.y = (unsigned)u0[2] | ((unsigned)u0[3] << 16);
        *(u32x2*)&Epk[eidx] = pk2;
    }
    __syncthreads();

    // ---- PV: D[c][w] ----
    int mt = wv;
    bf16x8 bE[4];
#pragma unroll
    for (int kt = 0; kt < 4; kt++)
        bE[kt] = *(const bf16x8*)&Epk[(((mt << 2) + kt) * 64 + l) << 3];

    bf16x8 ones;
    short ov = (m16 == 0) ? (short)0x3F80 : (short)0;
#pragma unroll
    for (int j = 0; j < 8; j++) ones[j] = ov;

    f32x4 acc[5];
#pragma unroll
    for (int i = 0; i < 5; i++) acc[i] = zero4;

#pragma unroll
    for (int ct = 0; ct < 4; ct++) {
#pragma unroll
        for (int kt = 0; kt < 4; kt++) {
            int slot = ((ct * 16 + m16) << 4) | ((((kt << 2) | kg)) ^ (m16 & 7));
            bf16x8 aV = *(const bf16x8*)&Vs[slot << 3];
            acc[ct] = __builtin_amdgcn_mfma_f32_16x16x32_bf16(aV, bE[kt], acc[ct], 0, 0, 0);
        }
    }
#pragma unroll
    for (int kt = 0; kt < 4; kt++)
        acc[4] = __builtin_amdgcn_mfma_f32_16x16x32_bf16(ones, bE[kt], acc[4], 0, 0, 0);

    long obase = (((long)(b * 128 + h)) * 128 + mt * 16 + m16) * 64;
#pragma unroll
    for (int ct = 0; ct < 4; ct++) {
        us4 pkd = { f2bf(acc[ct][0]), f2bf(acc[ct][1]), f2bf(acc[ct][2]), f2bf(acc[ct][3]) };
        *(us4*)&accWt[obase + ct * 16 + kg * 4] = pkd;
    }
    if (kg == 0)
        sW[(b * 128 + h) * 128 + mt * 16 + m16] = acc[4][0];
}

// ---------------------------------------------------------------------------
// Kernel 5: finalize. Block = (b, 16h x 32w tile).
// out[b][c][h][w] = gamma*(accHt[b][w][h][c] + accWt[b][h][w][c])/(sH+sW) + x.
// Thread owns (h,w): both acc reads are c-contiguous 128B; LDS transpose
// per 16-c chunk for the coalesced out write.
// ---------------------------------------------------------------------------
__global__ __launch_bounds__(512) void fin_kernel(
    const u16* __restrict__ accHt, const u16* __restrict__ accWt,
    const float* __restrict__ sH, const float* __restrict__ sW,
    const float* __restrict__ x, const float* __restrict__ gamma,
    float* __restrict__ out)
{
    __shared__ float sHs[32][17];
    __shared__ float sWs[16][33];
    __shared__ float T[16][16][36];

    int t = threadIdx.x;
    int bid = blockIdx.x;
    int fwg = ((bid & 7) << 6) | (bid >> 3);
    int b = fwg >> 5, tile = fwg & 31;
    int h0 = (tile >> 2) * 16, w0 = (tile & 3) * 32;

    if (t < 128) {
        int wl = t >> 2, h4 = (t & 3) * 4;
        *(float4*)&sHs[wl][h4] = *(const float4*)&sH[(b * 128 + w0 + wl) * 128 + h0 + h4];
    } else if (t < 256) {
        int i = t - 128;
        int hl = i >> 3, w4 = (i & 7) * 4;
        *(float4*)&sWs[hl][w4] = *(const float4*)&sW[(b * 128 + h0 + hl) * 128 + w0 + w4];
    }
    __syncthreads();

    int hh = t >> 5, ww = t & 31;
    float rsv = 1.0f / (sHs[ww][hh] + sWs[hh][ww]);
    float gr = gamma[0] * rsv;

    const u16* pH = accHt + (((long)(b * 128 + w0 + ww)) * 128 + h0 + hh) * 64;
    const u16* pW = accWt + (((long)(b * 128 + h0 + hh)) * 128 + w0 + ww) * 64;
    us8 rA[8], rB[8];
#pragma unroll
    for (int u = 0; u < 8; u++) {
        rA[u] = *(const us8*)&pH[u * 8];
        rB[u] = *(const us8*)&pW[u * 8];
    }

#pragma unroll
    for (int cc = 0; cc < 4; cc++) {
#pragma unroll
        for (int u = 0; u < 2; u++) {
            us8 a = rA[cc * 2 + u], bb = rB[cc * 2 + u];
#pragma unroll
            for (int j = 0; j < 8; j++) {
                float fa = __uint_as_float((unsigned)a[j] << 16);
                float fb = __uint_as_float((unsigned)bb[j] << 16);
                T[u * 8 + j][hh][ww] = gr * (fa + fb);
            }
        }
        __syncthreads();
        {
            int row = t >> 1, wseg = (t & 1) * 16;
            int cl = row >> 4, hl = row & 15;
            int c = cc * 16 + cl;
            long ga = (((long)(b * 64 + c)) << 14) + ((long)(h0 + hl) << 7) + w0 + wseg;
#pragma unroll
            for (int p4 = 0; p4 < 4; p4++) {
                float4 tv = *(float4*)&T[cl][hl][wseg + p4 * 4];
                float4 xv = *(const float4*)&x[ga + p4 * 4];
                float4 r;
                r.x = tv.x + xv.x;
                r.y = tv.y + xv.y;
                r.z = tv.z + xv.z;
                r.w = tv.w + xv.w;
                *(float4*)&out[ga + p4 * 4] = r;
            }
        }
        __syncthreads();
    }
}

extern "C" void kernel_launch(void* const* d_in, const int* in_sizes, int n_in,
                              void* d_out, int out_size, void* d_ws, size_t ws_size,
                              hipStream_t stream) {
    const float* x     = (const float*)d_in[0];
    const float* Wq    = (const float*)d_in[1];
    const float* bq    = (const float*)d_in[2];
    const float* Wk    = (const float*)d_in[3];
    const float* bk    = (const float*)d_in[4];
    const float* Wv    = (const float*)d_in[5];
    const float* bv    = (const float*)d_in[6];
    const float* gamma = (const float*)d_in[7];
    float* out = (float*)d_out;

    u16* vb16  = (u16*)d_ws;                 // 16,777,216 u16 (32MB)
    u16* vTc   = vb16 + 16777216;            // 16,777,216 u16 (32MB) — reused as accWt
    u16* qkTr  = vTc + 16777216;             // 4,194,304 u16 (8MB)
    u16* accHt = qkTr + 4194304;             // 16,777,216 u16 (32MB)
    float* sH  = (float*)(accHt + 16777216); // 262,144 f32 (1MB)
    float* sW  = sH + 262144;                // 262,144 f32 (1MB)
    u16* accWt = vTc;                        // alias: vTc dead after colH

    proj_kernel<<<1024, 256, 0, stream>>>(x, Wq, bq, Wk, bk, Wv, bv, vb16, qkTr);
    vtrans_kernel<<<16384, 256, 0, stream>>>(vb16, vTc);
    colH_kernel<<<2048, 512, 0, stream>>>(qkTr, vTc, accHt, sH);
    rowW_kernel<<<2048, 512, 0, stream>>>(qkTr, vb16, accWt, sW);
    fin_kernel<<<512, 512, 0, stream>>>(accHt, accWt, sH, sW, x, gamma, out);
}

// Round 5
// 130.090 us; speedup vs baseline: 3.8748x; 1.3180x over previous
//
#include <hip/hip_runtime.h>
#include <hip/hip_bf16.h>

// B=16, C=64, CQ=8, H=W=128
typedef unsigned short u16;
typedef __attribute__((ext_vector_type(8))) short    bf16x8;
typedef __attribute__((ext_vector_type(8))) unsigned short us8;
typedef __attribute__((ext_vector_type(4))) unsigned short us4;
typedef __attribute__((ext_vector_type(4))) float    f32x4;
typedef __attribute__((ext_vector_type(2))) unsigned int u32x2;

__device__ __forceinline__ u16 f2bf(float f) {
    unsigned u = __float_as_uint(f);
    return (u16)((u + 0x7FFFu + ((u >> 16) & 1u)) >> 16);
}

// ---------------------------------------------------------------------------
// Kernel 0: W prep. Packs Wv/Wq/Wk into bf16 B-frag slots
// Wpk[nt(5)][kt(2)][lane(64)][8]: B[k][n], n = c_out = nt*16+(l&15)
// (0..63 = v, 64..71 = q, 72..79 = k), k = kt*32+(l>>4)*8+j.
// biasf[80] = {bv, bq, bk}.
// ---------------------------------------------------------------------------
__global__ __launch_bounds__(256) void wprep_kernel(
    const float* __restrict__ Wq, const float* __restrict__ bq,
    const float* __restrict__ Wk, const float* __restrict__ bk,
    const float* __restrict__ Wv, const float* __restrict__ bv,
    u16* __restrict__ Wpk, float* __restrict__ biasf)
{
    int t = threadIdx.x;
    for (int s = t; s < 640; s += 256) {
        int nt = s >> 7;
        int kt = (s >> 6) & 1;
        int l  = s & 63;
        int n  = (nt << 4) | (l & 15);
        int k0 = kt * 32 + ((l >> 4) << 3);
        const float* row;
        if (n < 64) row = Wv + n * 64;
        else if (n < 72) row = Wq + (n - 64) * 64;
        else row = Wk + (n - 72) * 64;
        us8 o;
#pragma unroll
        for (int j = 0; j < 8; j++) o[j] = f2bf(row[k0 + j]);
        *(us8*)&Wpk[s * 8] = o;
    }
    if (t < 80) {
        float bb;
        if (t < 64) bb = bv[t];
        else if (t < 72) bb = bq[t - 64];
        else bb = bk[t - 72];
        biasf[t] = bb;
    }
}

// ---------------------------------------------------------------------------
// Kernel 1: projections via MFMA. Block = 256 pixels, 512 thr = 8 waves.
// D[pix][c_out] = x^T W^T + bias. Writes vb16[b][c][hw] (us4-coalesced)
// and qkTr[b][hw][16] = {q[8],k[8]}.
// ---------------------------------------------------------------------------
#define PH 258   // LDS x-tile row stride (u16); ==2 mod 4 -> conflict-free frags
__global__ __launch_bounds__(512) void proj_kernel(
    const float* __restrict__ x, const u16* __restrict__ Wpk,
    const float* __restrict__ biasf,
    u16* __restrict__ vb16, u16* __restrict__ qkTr)
{
    __shared__ u16 Xh[64 * PH];   // 33 KB

    int t = threadIdx.x;
    int bid = blockIdx.x;
    int wg = ((bid & 7) << 7) | (bid >> 3);   // b-matched XCD swizzle
    int b = wg >> 6;
    int hw0 = (wg & 63) << 8;
    const float* xb = x + ((long)b << 20) + hw0;

    // stage x tile (64c x 256pix) -> bf16 LDS, coalesced 1KB/instr
#pragma unroll
    for (int it = 0; it < 8; it++) {
        int c = it * 8 + (t >> 6);
        int pix = (t & 63) << 2;
        float4 xv = *(const float4*)&xb[(c << 14) + pix];
        unsigned lo = ((unsigned)f2bf(xv.y) << 16) | f2bf(xv.x);
        unsigned hi = ((unsigned)f2bf(xv.w) << 16) | f2bf(xv.z);
        unsigned* dst = (unsigned*)&Xh[c * PH + pix];
        dst[0] = lo; dst[1] = hi;
    }
    __syncthreads();

    int wv = t >> 6, l = t & 63;
    int m16 = l & 15, kg = l >> 4;
    int pixb = wv << 5;          // 32 pixels per wave

    // A-frags: A[m=pix][k=c], lane: pix = pixb+mt*16+m16, k = kt*32+kg*8+j
    bf16x8 af[2][2];
#pragma unroll
    for (int mt = 0; mt < 2; mt++) {
        int pix = pixb + (mt << 4) + m16;
#pragma unroll
        for (int kt = 0; kt < 2; kt++) {
            us8 a;
#pragma unroll
            for (int j = 0; j < 8; j++)
                a[j] = Xh[(kt * 32 + (kg << 3) + j) * PH + pix];
            af[mt][kt] = (bf16x8)a;
        }
    }

    f32x4 acc[2][5];
#pragma unroll
    for (int nt = 0; nt < 5; nt++) {
        float bb = biasf[(nt << 4) + m16];
        f32x4 binit = {bb, bb, bb, bb};
        bf16x8 b0 = *(const bf16x8*)&Wpk[(((nt << 1) + 0) << 9) + (l << 3)];
        bf16x8 b1 = *(const bf16x8*)&Wpk[(((nt << 1) + 1) << 9) + (l << 3)];
#pragma unroll
        for (int mt = 0; mt < 2; mt++) {
            f32x4 a_ = binit;
            a_ = __builtin_amdgcn_mfma_f32_16x16x32_bf16(af[mt][0], b0, a_, 0, 0, 0);
            a_ = __builtin_amdgcn_mfma_f32_16x16x32_bf16(af[mt][1], b1, a_, 0, 0, 0);
            acc[mt][nt] = a_;
        }
    }

    // stores: D row = pix = pixb+mt*16+kg*4+r, col = c_out = nt*16+m16
    long vbase = ((long)b << 20) + hw0;
#pragma unroll
    for (int mt = 0; mt < 2; mt++) {
        int pix0 = pixb + (mt << 4) + (kg << 2);
#pragma unroll
        for (int nt = 0; nt < 4; nt++) {
            int c = (nt << 4) + m16;
            us4 pkd = { f2bf(acc[mt][nt][0]), f2bf(acc[mt][nt][1]),
                        f2bf(acc[mt][nt][2]), f2bf(acc[mt][nt][3]) };
            *(us4*)&vb16[vbase + (c << 14) + pix0] = pkd;
        }
#pragma unroll
        for (int r = 0; r < 4; r++)
            qkTr[((((long)(b << 14)) + hw0 + pix0 + r) << 4) + m16] = f2bf(acc[mt][4][r]);
    }
}

// ---------------------------------------------------------------------------
// Kernel 2: v transpose: vb16[b][c][g][w] -> vTc[b][w][c][g] (bf16).
// ---------------------------------------------------------------------------
__global__ __launch_bounds__(256) void vtrans_kernel(
    const u16* __restrict__ vb16, u16* __restrict__ vTc)
{
    __shared__ u16 tile[32][33];
    int t = threadIdx.x;
    int bid = blockIdx.x;
    int vwg = ((bid & 7) << 11) | (bid >> 3);  // b-matched XCD swizzle
    int b = vwg >> 10;
    int c = (vwg >> 4) & 63;
    int g0 = ((vwg >> 2) & 3) * 32, w0 = (vwg & 3) * 32;
    const u16* src = vb16 + ((b * 64 + c) << 14);
#pragma unroll
    for (int it = 0; it < 4; it++) {
        int i = it * 8 + (t >> 5), j = t & 31;
        tile[i][j] = src[(g0 + i) * 128 + w0 + j];
    }
    __syncthreads();
    int j = t >> 3, i4 = (t & 7) * 4;
    us4 o = { tile[i4][j], tile[i4 + 1][j], tile[i4 + 2][j], tile[i4 + 3][j] };
    *(us4*)&vTc[((b * 128 + w0 + j) * 64 + c) * 128 + g0 + i4] = o;
}

// ---------------------------------------------------------------------------
// Kernel 3: column attention. Block (b,w), 512 thr = 8 waves.
// QK^T -> exp (diag masked) -> Epk (B-frag slots); PV = V^T(A) x E(B):
// D[c][h]. Writes accHt[b][w][h][c] bf16 (coalesced us4) + sH[b][w][h].
// ---------------------------------------------------------------------------
__global__ __launch_bounds__(512) void colH_kernel(
    const u16* __restrict__ qkTr, const u16* __restrict__ vTc,
    u16* __restrict__ accHt, float* __restrict__ sH)
{
    __shared__ u16 Qpk[129 * 8];       // slot 128 = zeros (K-dim pad)
    __shared__ u16 Kpk[129 * 8];
    __shared__ u16 Epk[2048 * 8];      // E B-frag slots [ht(8)][kt(4)][lane][8]
    __shared__ u16 Vs[1024 * 8];       // V^T tile [64c][16 slots][8], XOR-swizzled

    int t = threadIdx.x;
    int bid = blockIdx.x;
    int wg = ((bid & 7) << 8) | (bid >> 3);
    int b = wg >> 7, w = wg & 127;

    if (t < 128) {
        const u16* p = qkTr + (((long)((b << 14) + t * 128 + w)) << 4);
        *(us8*)&Qpk[t * 8] = *(const us8*)p;
        *(us8*)&Kpk[t * 8] = *(const us8*)(p + 8);
    } else if (t == 128) {
        us8 z = {0,0,0,0,0,0,0,0};
        *(us8*)&Qpk[128 * 8] = z;
        *(us8*)&Kpk[128 * 8] = z;
    }

    // stage V^T tile: LDS linear, source chunk index XOR-swizzled
    const u16* vB = vTc + ((long)(b * 128 + w) << 13);
#pragma unroll
    for (int m = t; m < 1024; m += 512) {
        int c = m >> 4, s = m & 15;
        int src = (c << 4) | (s & 8) | ((s ^ c) & 7);
        *(us8*)&Vs[m << 3] = *(const us8*)&vB[src << 3];
    }
    __syncthreads();

    int wv = t >> 6, l = t & 63;
    int m16 = l & 15, kg = l >> 4;
    f32x4 zero4 = {0.f, 0.f, 0.f, 0.f};

    // ---- QK^T: wave owns g-tile gt=wv; E[g][h] ----
    int gt = wv;
    bf16x8 afr;
    { int sl = (kg == 0) ? (gt * 16 + m16) : 128;
      afr = *(const bf16x8*)&Kpk[sl * 8]; }
    int kgr = ((gt & 1) << 1) | (kg >> 1);
    int jb  = (kg & 1) << 2;
    int gbase = gt * 16 + kg * 4;
#pragma unroll
    for (int ht = 0; ht < 8; ht++) {
        int slB = (kg == 0) ? (ht * 16 + m16) : 128;
        bf16x8 bfr = *(const bf16x8*)&Qpk[slB * 8];
        f32x4 e = __builtin_amdgcn_mfma_f32_16x16x32_bf16(afr, bfr, zero4, 0, 0, 0);
        u16 u0[4];
#pragma unroll
        for (int r = 0; r < 4; r++) {
            int g = gbase + r, h = ht * 16 + m16;
            float val = (g == h) ? 0.f : __expf(e[r]);
            u0[r] = f2bf(val);
        }
        int eidx = ((((ht << 2) | (gt >> 1)) * 64 + kgr * 16 + m16) << 3) + jb;
        u32x2 pk2;
        pk2.x = (unsigned)u0[0] | ((unsigned)u0[1] << 16);
        pk2.y = (unsigned)u0[2] | ((unsigned)u0[3] << 16);
        *(u32x2*)&Epk[eidx] = pk2;
    }
    __syncthreads();

    // ---- PV: D[c][h] = V^T x E. wave owns h-tile mt=wv ----
    int mt = wv;
    bf16x8 bE[4];
#pragma unroll
    for (int kt = 0; kt < 4; kt++)
        bE[kt] = *(const bf16x8*)&Epk[(((mt << 2) + kt) * 64 + l) << 3];

    bf16x8 ones;
    short ov = (m16 == 0) ? (short)0x3F80 : (short)0;
#pragma unroll
    for (int j = 0; j < 8; j++) ones[j] = ov;

    f32x4 acc[5];
#pragma unroll
    for (int i = 0; i < 5; i++) acc[i] = zero4;

#pragma unroll
    for (int ct = 0; ct < 4; ct++) {
#pragma unroll
        for (int kt = 0; kt < 4; kt++) {
            int slot = ((ct * 16 + m16) << 4) | ((((kt << 2) | kg)) ^ (m16 & 7));
            bf16x8 aV = *(const bf16x8*)&Vs[slot << 3];
            acc[ct] = __builtin_amdgcn_mfma_f32_16x16x32_bf16(aV, bE[kt], acc[ct], 0, 0, 0);
        }
    }
#pragma unroll
    for (int kt = 0; kt < 4; kt++)
        acc[4] = __builtin_amdgcn_mfma_f32_16x16x32_bf16(ones, bE[kt], acc[4], 0, 0, 0);

    // epilogue: accHt[b][w][h][c] bf16 (8B-coalesced), sH[b][w][h]
    long obase = (((long)(b * 128 + w)) * 128 + mt * 16 + m16) * 64;
#pragma unroll
    for (int ct = 0; ct < 4; ct++) {
        us4 pkd = { f2bf(acc[ct][0]), f2bf(acc[ct][1]), f2bf(acc[ct][2]), f2bf(acc[ct][3]) };
        *(us4*)&accHt[obase + ct * 16 + kg * 4] = pkd;
    }
    if (kg == 0)
        sH[(b * 128 + w) * 128 + mt * 16 + m16] = acc[4][0];
}

// ---------------------------------------------------------------------------
// Kernel 4: row attention (mirror). Writes accWt[b][h][w][c] bf16 + sW[b][h][w].
// ---------------------------------------------------------------------------
__global__ __launch_bounds__(512) void rowW_kernel(
    const u16* __restrict__ qkTr, const u16* __restrict__ vb16,
    u16* __restrict__ accWt, float* __restrict__ sW)
{
    __shared__ u16 Qpk[129 * 8];
    __shared__ u16 Kpk[129 * 8];
    __shared__ u16 Epk[2048 * 8];
    __shared__ u16 Vs[1024 * 8];

    int t = threadIdx.x;
    int bid = blockIdx.x;
    int wg = ((bid & 7) << 8) | (bid >> 3);
    int b = wg >> 7, h = wg & 127;

    if (t < 128) {
        const u16* p = qkTr + (((long)((b << 14) + h * 128 + t)) << 4);
        *(us8*)&Qpk[t * 8] = *(const us8*)p;
        *(us8*)&Kpk[t * 8] = *(const us8*)(p + 8);
    } else if (t == 128) {
        us8 z = {0,0,0,0,0,0,0,0};
        *(us8*)&Qpk[128 * 8] = z;
        *(us8*)&Kpk[128 * 8] = z;
    }

    const u16* vB = vb16 + ((long)b << 20) + (h << 7);
#pragma unroll
    for (int m = t; m < 1024; m += 512) {
        int c = m >> 4, s = m & 15;
        int src = (s & 8) | ((s ^ c) & 7);
        *(us8*)&Vs[m << 3] = *(const us8*)&vB[((long)c << 14) + (src << 3)];
    }
    __syncthreads();

    int wv = t >> 6, l = t & 63;
    int m16 = l & 15, kg = l >> 4;
    f32x4 zero4 = {0.f, 0.f, 0.f, 0.f};

    // ---- QK^T: E[v][w], no diagonal mask ----
    int gt = wv;
    bf16x8 afr;
    { int sl = (kg == 0) ? (gt * 16 + m16) : 128;
      afr = *(const bf16x8*)&Kpk[sl * 8]; }
    int kgr = ((gt & 1) << 1) | (kg >> 1);
    int jb  = (kg & 1) << 2;
#pragma unroll
    for (int ht = 0; ht < 8; ht++) {
        int slB = (kg == 0) ? (ht * 16 + m16) : 128;
        bf16x8 bfr = *(const bf16x8*)&Qpk[slB * 8];
        f32x4 e = __builtin_amdgcn_mfma_f32_16x16x32_bf16(afr, bfr, zero4, 0, 0, 0);
        u16 u0[4];
#pragma unroll
        for (int r = 0; r < 4; r++) u0[r] = f2bf(__expf(e[r]));
        int eidx = ((((ht << 2) | (gt >> 1)) * 64 + kgr * 16 + m16) << 3) + jb;
        u32x2 pk2;
        pk2.x = (unsigned)u0[0] | ((unsigned)u0[1] << 16);
        pk2.y = (unsigned)u0[2] | ((unsigned)u0[3] << 16);
        *(u32x2*)&Epk[eidx] = pk2;
    }
    __syncthreads();

    // ---- PV: D[c][w] ----
    int mt = wv;
    bf16x8 bE[4];
#pragma unroll
    for (int kt = 0; kt < 4; kt++)
        bE[kt] = *(const bf16x8*)&Epk[(((mt << 2) + kt) * 64 + l) << 3];

    bf16x8 ones;
    short ov = (m16 == 0) ? (short)0x3F80 : (short)0;
#pragma unroll
    for (int j = 0; j < 8; j++) ones[j] = ov;

    f32x4 acc[5];
#pragma unroll
    for (int i = 0; i < 5; i++) acc[i] = zero4;

#pragma unroll
    for (int ct = 0; ct < 4; ct++) {
#pragma unroll
        for (int kt = 0; kt < 4; kt++) {
            int slot = ((ct * 16 + m16) << 4) | ((((kt << 2) | kg)) ^ (m16 & 7));
            bf16x8 aV = *(const bf16x8*)&Vs[slot << 3];
            acc[ct] = __builtin_amdgcn_mfma_f32_16x16x32_bf16(aV, bE[kt], acc[ct], 0, 0, 0);
        }
    }
#pragma unroll
    for (int kt = 0; kt < 4; kt++)
        acc[4] = __builtin_amdgcn_mfma_f32_16x16x32_bf16(ones, bE[kt], acc[4], 0, 0, 0);

    long obase = (((long)(b * 128 + h)) * 128 + mt * 16 + m16) * 64;
#pragma unroll
    for (int ct = 0; ct < 4; ct++) {
        us4 pkd = { f2bf(acc[ct][0]), f2bf(acc[ct][1]), f2bf(acc[ct][2]), f2bf(acc[ct][3]) };
        *(us4*)&accWt[obase + ct * 16 + kg * 4] = pkd;
    }
    if (kg == 0)
        sW[(b * 128 + h) * 128 + mt * 16 + m16] = acc[4][0];
}

// ---------------------------------------------------------------------------
// Kernel 5: finalize. Block = (b, 16h x 32w tile).
// out[b][c][h][w] = gamma*(accHt[b][w][h][c] + accWt[b][h][w][c])/(sH+sW) + x.
// ---------------------------------------------------------------------------
__global__ __launch_bounds__(512) void fin_kernel(
    const u16* __restrict__ accHt, const u16* __restrict__ accWt,
    const float* __restrict__ sH, const float* __restrict__ sW,
    const float* __restrict__ x, const float* __restrict__ gamma,
    float* __restrict__ out)
{
    __shared__ float sHs[32][17];
    __shared__ float sWs[16][33];
    __shared__ float T[16][16][36];

    int t = threadIdx.x;
    int bid = blockIdx.x;
    int fwg = ((bid & 7) << 6) | (bid >> 3);
    int b = fwg >> 5, tile = fwg & 31;
    int h0 = (tile >> 2) * 16, w0 = (tile & 3) * 32;

    if (t < 128) {
        int wl = t >> 2, h4 = (t & 3) * 4;
        *(float4*)&sHs[wl][h4] = *(const float4*)&sH[(b * 128 + w0 + wl) * 128 + h0 + h4];
    } else if (t < 256) {
        int i = t - 128;
        int hl = i >> 3, w4 = (i & 7) * 4;
        *(float4*)&sWs[hl][w4] = *(const float4*)&sW[(b * 128 + h0 + hl) * 128 + w0 + w4];
    }
    __syncthreads();

    int hh = t >> 5, ww = t & 31;
    float rsv = 1.0f / (sHs[ww][hh] + sWs[hh][ww]);
    float gr = gamma[0] * rsv;

    const u16* pH = accHt + (((long)(b * 128 + w0 + ww)) * 128 + h0 + hh) * 64;
    const u16* pW = accWt + (((long)(b * 128 + h0 + hh)) * 128 + w0 + ww) * 64;
    us8 rA[8], rB[8];
#pragma unroll
    for (int u = 0; u < 8; u++) {
        rA[u] = *(const us8*)&pH[u * 8];
        rB[u] = *(const us8*)&pW[u * 8];
    }

#pragma unroll
    for (int cc = 0; cc < 4; cc++) {
#pragma unroll
        for (int u = 0; u < 2; u++) {
            us8 a = rA[cc * 2 + u], bb = rB[cc * 2 + u];
#pragma unroll
            for (int j = 0; j < 8; j++) {
                float fa = __uint_as_float((unsigned)a[j] << 16);
                float fb = __uint_as_float((unsigned)bb[j] << 16);
                T[u * 8 + j][hh][ww] = gr * (fa + fb);
            }
        }
        __syncthreads();
        {
            int row = t >> 1, wseg = (t & 1) * 16;
            int cl = row >> 4, hl = row & 15;
            int c = cc * 16 + cl;
            long ga = (((long)(b * 64 + c)) << 14) + ((long)(h0 + hl) << 7) + w0 + wseg;
#pragma unroll
            for (int p4 = 0; p4 < 4; p4++) {
                float4 tv = *(float4*)&T[cl][hl][wseg + p4 * 4];
                float4 xv = *(const float4*)&x[ga + p4 * 4];
                float4 r;
                r.x = tv.x + xv.x;
                r.y = tv.y + xv.y;
                r.z = tv.z + xv.z;
                r.w = tv.w + xv.w;
                *(float4*)&out[ga + p4 * 4] = r;
            }
        }
        __syncthreads();
    }
}

extern "C" void kernel_launch(void* const* d_in, const int* in_sizes, int n_in,
                              void* d_out, int out_size, void* d_ws, size_t ws_size,
                              hipStream_t stream) {
    const float* x     = (const float*)d_in[0];
    const float* Wq    = (const float*)d_in[1];
    const float* bq    = (const float*)d_in[2];
    const float* Wk    = (const float*)d_in[3];
    const float* bk    = (const float*)d_in[4];
    const float* Wv    = (const float*)d_in[5];
    const float* bv    = (const float*)d_in[6];
    const float* gamma = (const float*)d_in[7];
    float* out = (float*)d_out;

    u16* vb16  = (u16*)d_ws;                 // 16,777,216 u16 (32MB)
    u16* vTc   = vb16 + 16777216;            // 16,777,216 u16 (32MB) — reused as accWt
    u16* qkTr  = vTc + 16777216;             // 4,194,304 u16 (8MB)
    u16* accHt = qkTr + 4194304;             // 16,777,216 u16 (32MB)
    float* sH  = (float*)(accHt + 16777216); // 262,144 f32 (1MB)
    float* sW  = sH + 262144;                // 262,144 f32 (1MB)
    u16* Wpk   = (u16*)(sW + 262144);        // 5,120 u16
    float* biasf = (float*)(Wpk + 5120);     // 80 f32
    u16* accWt = vTc;                        // alias: vTc dead after colH

    wprep_kernel<<<1, 256, 0, stream>>>(Wq, bq, Wk, bk, Wv, bv, Wpk, biasf);
    proj_kernel<<<1024, 512, 0, stream>>>(x, Wpk, biasf, vb16, qkTr);
    vtrans_kernel<<<16384, 256, 0, stream>>>(vb16, vTc);
    colH_kernel<<<2048, 512, 0, stream>>>(qkTr, vTc, accHt, sH);
    rowW_kernel<<<2048, 512, 0, stream>>>(qkTr, vb16, accWt, sW);
    fin_kernel<<<512, 512, 0, stream>>>(accHt, accWt, sH, sW, x, gamma, out);
}

// Round 6
// 111.686 us; speedup vs baseline: 4.5134x; 1.1648x over previous
//
#include <hip/hip_runtime.h>
#include <hip/hip_bf16.h>

// B=16, C=64, CQ=8, H=W=128
typedef unsigned short u16;
typedef __attribute__((ext_vector_type(8))) short    bf16x8;
typedef __attribute__((ext_vector_type(8))) unsigned short us8;
typedef __attribute__((ext_vector_type(4))) unsigned short us4;
typedef __attribute__((ext_vector_type(4))) float    f32x4;
typedef __attribute__((ext_vector_type(2))) unsigned int u32x2;

__device__ __forceinline__ u16 f2bf(float f) {
    unsigned u = __float_as_uint(f);
    return (u16)((u + 0x7FFFu + ((u >> 16) & 1u)) >> 16);
}
__device__ __forceinline__ float bf2f(u16 v) {
    return __uint_as_float((unsigned)v << 16);
}

// ---------------------------------------------------------------------------
// Kernel 0: W prep. Packs Wv/Wq/Wk into bf16 B-frag slots
// Wpk[nt(5)][kt(2)][lane(64)][8]; biasf[80] = {bv, bq, bk}.
// ---------------------------------------------------------------------------
__global__ __launch_bounds__(256) void wprep_kernel(
    const float* __restrict__ Wq, const float* __restrict__ bq,
    const float* __restrict__ Wk, const float* __restrict__ bk,
    const float* __restrict__ Wv, const float* __restrict__ bv,
    u16* __restrict__ Wpk, float* __restrict__ biasf)
{
    int t = threadIdx.x;
    for (int s = t; s < 640; s += 256) {
        int nt = s >> 7;
        int kt = (s >> 6) & 1;
        int l  = s & 63;
        int n  = (nt << 4) | (l & 15);
        int k0 = kt * 32 + ((l >> 4) << 3);
        const float* row;
        if (n < 64) row = Wv + n * 64;
        else if (n < 72) row = Wq + (n - 64) * 64;
        else row = Wk + (n - 72) * 64;
        us8 o;
#pragma unroll
        for (int j = 0; j < 8; j++) o[j] = f2bf(row[k0 + j]);
        *(us8*)&Wpk[s * 8] = o;
    }
    if (t < 80) {
        float bb;
        if (t < 64) bb = bv[t];
        else if (t < 72) bb = bq[t - 64];
        else bb = bk[t - 72];
        biasf[t] = bb;
    }
}

// ---------------------------------------------------------------------------
// Kernel 1: projections via MFMA. Block = 256 pixels, 512 thr = 8 waves.
// ---------------------------------------------------------------------------
#define PH 258   // LDS x-tile row stride (u16); ==2 mod 4 -> conflict-free frags
__global__ __launch_bounds__(512) void proj_kernel(
    const float* __restrict__ x, const u16* __restrict__ Wpk,
    const float* __restrict__ biasf,
    u16* __restrict__ vb16, u16* __restrict__ qkTr)
{
    __shared__ u16 Xh[64 * PH];   // 33 KB

    int t = threadIdx.x;
    int bid = blockIdx.x;
    int wg = ((bid & 7) << 7) | (bid >> 3);   // b-matched XCD swizzle
    int b = wg >> 6;
    int hw0 = (wg & 63) << 8;
    const float* xb = x + ((long)b << 20) + hw0;

#pragma unroll
    for (int it = 0; it < 8; it++) {
        int c = it * 8 + (t >> 6);
        int pix = (t & 63) << 2;
        float4 xv = *(const float4*)&xb[(c << 14) + pix];
        unsigned lo = ((unsigned)f2bf(xv.y) << 16) | f2bf(xv.x);
        unsigned hi = ((unsigned)f2bf(xv.w) << 16) | f2bf(xv.z);
        unsigned* dst = (unsigned*)&Xh[c * PH + pix];
        dst[0] = lo; dst[1] = hi;
    }
    __syncthreads();

    int wv = t >> 6, l = t & 63;
    int m16 = l & 15, kg = l >> 4;
    int pixb = wv << 5;

    bf16x8 af[2][2];
#pragma unroll
    for (int mt = 0; mt < 2; mt++) {
        int pix = pixb + (mt << 4) + m16;
#pragma unroll
        for (int kt = 0; kt < 2; kt++) {
            us8 a;
#pragma unroll
            for (int j = 0; j < 8; j++)
                a[j] = Xh[(kt * 32 + (kg << 3) + j) * PH + pix];
            af[mt][kt] = (bf16x8)a;
        }
    }

    f32x4 acc[2][5];
#pragma unroll
    for (int nt = 0; nt < 5; nt++) {
        float bb = biasf[(nt << 4) + m16];
        f32x4 binit = {bb, bb, bb, bb};
        bf16x8 b0 = *(const bf16x8*)&Wpk[(((nt << 1) + 0) << 9) + (l << 3)];
        bf16x8 b1 = *(const bf16x8*)&Wpk[(((nt << 1) + 1) << 9) + (l << 3)];
#pragma unroll
        for (int mt = 0; mt < 2; mt++) {
            f32x4 a_ = binit;
            a_ = __builtin_amdgcn_mfma_f32_16x16x32_bf16(af[mt][0], b0, a_, 0, 0, 0);
            a_ = __builtin_amdgcn_mfma_f32_16x16x32_bf16(af[mt][1], b1, a_, 0, 0, 0);
            acc[mt][nt] = a_;
        }
    }

    long vbase = ((long)b << 20) + hw0;
#pragma unroll
    for (int mt = 0; mt < 2; mt++) {
        int pix0 = pixb + (mt << 4) + (kg << 2);
#pragma unroll
        for (int nt = 0; nt < 4; nt++) {
            int c = (nt << 4) + m16;
            us4 pkd = { f2bf(acc[mt][nt][0]), f2bf(acc[mt][nt][1]),
                        f2bf(acc[mt][nt][2]), f2bf(acc[mt][nt][3]) };
            *(us4*)&vb16[vbase + (c << 14) + pix0] = pkd;
        }
#pragma unroll
        for (int r = 0; r < 4; r++)
            qkTr[((((long)(b << 14)) + hw0 + pix0 + r) << 4) + m16] = f2bf(acc[mt][4][r]);
    }
}

// ---------------------------------------------------------------------------
// Kernel 2: v transpose: vb16[b][c][g][w] -> vTc[b][w][c][g] (bf16).
// ---------------------------------------------------------------------------
__global__ __launch_bounds__(256) void vtrans_kernel(
    const u16* __restrict__ vb16, u16* __restrict__ vTc)
{
    __shared__ u16 tile[32][33];
    int t = threadIdx.x;
    int bid = blockIdx.x;
    int vwg = ((bid & 7) << 11) | (bid >> 3);  // b-matched XCD swizzle
    int b = vwg >> 10;
    int c = (vwg >> 4) & 63;
    int g0 = ((vwg >> 2) & 3) * 32, w0 = (vwg & 3) * 32;
    const u16* src = vb16 + ((b * 64 + c) << 14);
#pragma unroll
    for (int it = 0; it < 4; it++) {
        int i = it * 8 + (t >> 5), j = t & 31;
        tile[i][j] = src[(g0 + i) * 128 + w0 + j];
    }
    __syncthreads();
    int j = t >> 3, i4 = (t & 7) * 4;
    us4 o = { tile[i4][j], tile[i4 + 1][j], tile[i4 + 2][j], tile[i4 + 3][j] };
    *(us4*)&vTc[((b * 128 + w0 + j) * 64 + c) * 128 + g0 + i4] = o;
}

// ---------------------------------------------------------------------------
// Kernel 3: column attention. Block (b,w), 512 thr = 8 waves.
// QK^T -> exp (diag masked) -> Epk; PV = V^T(A) x E(B): D[c][h].
// Writes accHt[b][w][h][c] bf16 + sH[b][w][h].
// ---------------------------------------------------------------------------
__global__ __launch_bounds__(512) void colH_kernel(
    const u16* __restrict__ qkTr, const u16* __restrict__ vTc,
    u16* __restrict__ accHt, float* __restrict__ sH)
{
    __shared__ u16 Qpk[129 * 8];
    __shared__ u16 Kpk[129 * 8];
    __shared__ u16 Epk[2048 * 8];
    __shared__ u16 Vs[1024 * 8];

    int t = threadIdx.x;
    int bid = blockIdx.x;
    int wg = ((bid & 7) << 8) | (bid >> 3);
    int b = wg >> 7, w = wg & 127;

    if (t < 128) {
        const u16* p = qkTr + (((long)((b << 14) + t * 128 + w)) << 4);
        *(us8*)&Qpk[t * 8] = *(const us8*)p;
        *(us8*)&Kpk[t * 8] = *(const us8*)(p + 8);
    } else if (t == 128) {
        us8 z = {0,0,0,0,0,0,0,0};
        *(us8*)&Qpk[128 * 8] = z;
        *(us8*)&Kpk[128 * 8] = z;
    }

    const u16* vB = vTc + ((long)(b * 128 + w) << 13);
#pragma unroll
    for (int m = t; m < 1024; m += 512) {
        int c = m >> 4, s = m & 15;
        int src = (c << 4) | (s & 8) | ((s ^ c) & 7);
        *(us8*)&Vs[m << 3] = *(const us8*)&vB[src << 3];
    }
    __syncthreads();

    int wv = t >> 6, l = t & 63;
    int m16 = l & 15, kg = l >> 4;
    f32x4 zero4 = {0.f, 0.f, 0.f, 0.f};

    int gt = wv;
    bf16x8 afr;
    { int sl = (kg == 0) ? (gt * 16 + m16) : 128;
      afr = *(const bf16x8*)&Kpk[sl * 8]; }
    int kgr = ((gt & 1) << 1) | (kg >> 1);
    int jb  = (kg & 1) << 2;
    int gbase = gt * 16 + kg * 4;
#pragma unroll
    for (int ht = 0; ht < 8; ht++) {
        int slB = (kg == 0) ? (ht * 16 + m16) : 128;
        bf16x8 bfr = *(const bf16x8*)&Qpk[slB * 8];
        f32x4 e = __builtin_amdgcn_mfma_f32_16x16x32_bf16(afr, bfr, zero4, 0, 0, 0);
        u16 u0[4];
#pragma unroll
        for (int r = 0; r < 4; r++) {
            int g = gbase + r, h = ht * 16 + m16;
            float val = (g == h) ? 0.f : __expf(e[r]);
            u0[r] = f2bf(val);
        }
        int eidx = ((((ht << 2) | (gt >> 1)) * 64 + kgr * 16 + m16) << 3) + jb;
        u32x2 pk2;
        pk2.x = (unsigned)u0[0] | ((unsigned)u0[1] << 16);
        pk2.y = (unsigned)u0[2] | ((unsigned)u0[3] << 16);
        *(u32x2*)&Epk[eidx] = pk2;
    }
    __syncthreads();

    int mt = wv;
    bf16x8 bE[4];
#pragma unroll
    for (int kt = 0; kt < 4; kt++)
        bE[kt] = *(const bf16x8*)&Epk[(((mt << 2) + kt) * 64 + l) << 3];

    bf16x8 ones;
    short ov = (m16 == 0) ? (short)0x3F80 : (short)0;
#pragma unroll
    for (int j = 0; j < 8; j++) ones[j] = ov;

    f32x4 acc[5];
#pragma unroll
    for (int i = 0; i < 5; i++) acc[i] = zero4;

#pragma unroll
    for (int ct = 0; ct < 4; ct++) {
#pragma unroll
        for (int kt = 0; kt < 4; kt++) {
            int slot = ((ct * 16 + m16) << 4) | ((((kt << 2) | kg)) ^ (m16 & 7));
            bf16x8 aV = *(const bf16x8*)&Vs[slot << 3];
            acc[ct] = __builtin_amdgcn_mfma_f32_16x16x32_bf16(aV, bE[kt], acc[ct], 0, 0, 0);
        }
    }
#pragma unroll
    for (int kt = 0; kt < 4; kt++)
        acc[4] = __builtin_amdgcn_mfma_f32_16x16x32_bf16(ones, bE[kt], acc[4], 0, 0, 0);

    long obase = (((long)(b * 128 + w)) * 128 + mt * 16 + m16) * 64;
#pragma unroll
    for (int ct = 0; ct < 4; ct++) {
        us4 pkd = { f2bf(acc[ct][0]), f2bf(acc[ct][1]), f2bf(acc[ct][2]), f2bf(acc[ct][3]) };
        *(us4*)&accHt[obase + ct * 16 + kg * 4] = pkd;
    }
    if (kg == 0)
        sH[(b * 128 + w) * 128 + mt * 16 + m16] = acc[4][0];
}

// ---------------------------------------------------------------------------
// Kernel 4: row attention + fused finalize. Block (b,h), 512 thr = 8 waves.
// After PV (accW in regs): stage accW in LDS outS, combine with accHt slice
// and 1/(sH+sW), then coalesced out = gamma*(...)+x.
// ---------------------------------------------------------------------------
__global__ __launch_bounds__(512) void rowW_fin_kernel(
    const u16* __restrict__ qkTr, const u16* __restrict__ vb16,
    const u16* __restrict__ accHt, const float* __restrict__ sH,
    const float* __restrict__ x, const float* __restrict__ gamma,
    float* __restrict__ out)
{
    __shared__ u16 Qpk[129 * 8];
    __shared__ u16 Kpk[129 * 8];
    __shared__ union FU {
        struct { u16 Epk[2048 * 8]; u16 Vs[1024 * 8]; } s;          // 48 KB
        struct { float outS[64 * 132]; float sWs[128]; float grs[128]; } f;
    } uu;

    int t = threadIdx.x;
    int bid = blockIdx.x;
    int wg = ((bid & 7) << 8) | (bid >> 3);
    int b = wg >> 7, h = wg & 127;
    float gm = gamma[0];

    if (t < 128) {
        const u16* p = qkTr + (((long)((b << 14) + h * 128 + t)) << 4);
        *(us8*)&Qpk[t * 8] = *(const us8*)p;
        *(us8*)&Kpk[t * 8] = *(const us8*)(p + 8);
    } else if (t == 128) {
        us8 z = {0,0,0,0,0,0,0,0};
        *(us8*)&Qpk[128 * 8] = z;
        *(us8*)&Kpk[128 * 8] = z;
    }

    const u16* vB = vb16 + ((long)b << 20) + (h << 7);
#pragma unroll
    for (int m = t; m < 1024; m += 512) {
        int c = m >> 4, s = m & 15;
        int src = (s & 8) | ((s ^ c) & 7);
        *(us8*)&uu.s.Vs[m << 3] = *(const us8*)&vB[((long)c << 14) + (src << 3)];
    }
    __syncthreads();

    int wv = t >> 6, l = t & 63;
    int m16 = l & 15, kg = l >> 4;
    f32x4 zero4 = {0.f, 0.f, 0.f, 0.f};

    // ---- QK^T: E[v][w], no diagonal mask ----
    int gt = wv;
    bf16x8 afr;
    { int sl = (kg == 0) ? (gt * 16 + m16) : 128;
      afr = *(const bf16x8*)&Kpk[sl * 8]; }
    int kgr = ((gt & 1) << 1) | (kg >> 1);
    int jb  = (kg & 1) << 2;
#pragma unroll
    for (int ht = 0; ht < 8; ht++) {
        int slB = (kg == 0) ? (ht * 16 + m16) : 128;
        bf16x8 bfr = *(const bf16x8*)&Qpk[slB * 8];
        f32x4 e = __builtin_amdgcn_mfma_f32_16x16x32_bf16(afr, bfr, zero4, 0, 0, 0);
        u16 u0[4];
#pragma unroll
        for (int r = 0; r < 4; r++) u0[r] = f2bf(__expf(e[r]));
        int eidx = ((((ht << 2) | (gt >> 1)) * 64 + kgr * 16 + m16) << 3) + jb;
        u32x2 pk2;
        pk2.x = (unsigned)u0[0] | ((unsigned)u0[1] << 16);
        pk2.y = (unsigned)u0[2] | ((unsigned)u0[3] << 16);
        *(u32x2*)&uu.s.Epk[eidx] = pk2;
    }
    __syncthreads();

    // ---- PV: D[c][w] ----
    int mt = wv;
    bf16x8 bE[4];
#pragma unroll
    for (int kt = 0; kt < 4; kt++)
        bE[kt] = *(const bf16x8*)&uu.s.Epk[(((mt << 2) + kt) * 64 + l) << 3];

    bf16x8 ones;
    short ov = (m16 == 0) ? (short)0x3F80 : (short)0;
#pragma unroll
    for (int j = 0; j < 8; j++) ones[j] = ov;

    f32x4 acc[5];
#pragma unroll
    for (int i = 0; i < 5; i++) acc[i] = zero4;

#pragma unroll
    for (int ct = 0; ct < 4; ct++) {
#pragma unroll
        for (int kt = 0; kt < 4; kt++) {
            int slot = ((ct * 16 + m16) << 4) | ((((kt << 2) | kg)) ^ (m16 & 7));
            bf16x8 aV = *(const bf16x8*)&uu.s.Vs[slot << 3];
            acc[ct] = __builtin_amdgcn_mfma_f32_16x16x32_bf16(aV, bE[kt], acc[ct], 0, 0, 0);
        }
    }
#pragma unroll
    for (int kt = 0; kt < 4; kt++)
        acc[4] = __builtin_amdgcn_mfma_f32_16x16x32_bf16(ones, bE[kt], acc[4], 0, 0, 0);

    __syncthreads();   // Epk/Vs dead; union flips to outS/sWs/grs

    // ---- F0: stage accW + sW into LDS ----
    int wcol = mt * 16 + m16;
#pragma unroll
    for (int ct = 0; ct < 4; ct++)
#pragma unroll
        for (int r = 0; r < 4; r++)
            uu.f.outS[(ct * 16 + kg * 4 + r) * 132 + wcol] = acc[ct][r];
    if (kg == 0) uu.f.sWs[wcol] = acc[4][0];
    __syncthreads();

    // ---- F1: issue accHt loads + compute gr[w] ----
    int i0 = t, i1 = t + 512;
    int w0 = i0 & 127, c00 = (i0 >> 7) << 3;
    int w1 = i1 & 127, c01 = (i1 >> 7) << 3;
    us8 hA0 = *(const us8*)&accHt[((((long)(b * 128 + w0)) * 128 + h) << 6) + c00];
    us8 hA1 = *(const us8*)&accHt[((((long)(b * 128 + w1)) * 128 + h) << 6) + c01];
    // prefetch x for the epilogue
    long obase = ((long)b << 20) + (h << 7);
    float4 xv[4];
#pragma unroll
    for (int p = 0; p < 4; p++) {
        int q = t + 512 * p;
        int c = q >> 5, w4 = (q & 31) << 2;
        xv[p] = *(const float4*)&x[obase + ((long)c << 14) + w4];
    }
    if (t < 128)
        uu.f.grs[t] = gm / (sH[(b * 128 + t) * 128 + h] + uu.f.sWs[t]);
    __syncthreads();

    // ---- F2: combine accH into outS ----
    {
        float g0 = uu.f.grs[w0], g1 = uu.f.grs[w1];
#pragma unroll
        for (int j = 0; j < 8; j++) {
            float* p = &uu.f.outS[(c00 + j) * 132 + w0];
            *p = g0 * (*p + bf2f(hA0[j]));
        }
#pragma unroll
        for (int j = 0; j < 8; j++) {
            float* p = &uu.f.outS[(c01 + j) * 132 + w1];
            *p = g1 * (*p + bf2f(hA1[j]));
        }
    }
    __syncthreads();

    // ---- F3: coalesced out = outS + x ----
#pragma unroll
    for (int p = 0; p < 4; p++) {
        int q = t + 512 * p;
        int c = q >> 5, w4 = (q & 31) << 2;
        float4 tv = *(float4*)&uu.f.outS[c * 132 + w4];
        float4 r;
        r.x = tv.x + xv[p].x;
        r.y = tv.y + xv[p].y;
        r.z = tv.z + xv[p].z;
        r.w = tv.w + xv[p].w;
        *(float4*)&out[obase + ((long)c << 14) + w4] = r;
    }
}

extern "C" void kernel_launch(void* const* d_in, const int* in_sizes, int n_in,
                              void* d_out, int out_size, void* d_ws, size_t ws_size,
                              hipStream_t stream) {
    const float* x     = (const float*)d_in[0];
    const float* Wq    = (const float*)d_in[1];
    const float* bq    = (const float*)d_in[2];
    const float* Wk    = (const float*)d_in[3];
    const float* bk    = (const float*)d_in[4];
    const float* Wv    = (const float*)d_in[5];
    const float* bv    = (const float*)d_in[6];
    const float* gamma = (const float*)d_in[7];
    float* out = (float*)d_out;

    u16* vb16  = (u16*)d_ws;                 // 16,777,216 u16 (32MB)
    u16* vTc   = vb16 + 16777216;            // 16,777,216 u16 (32MB)
    u16* qkTr  = vTc + 16777216;             // 4,194,304 u16 (8MB)
    u16* accHt = qkTr + 4194304;             // 16,777,216 u16 (32MB)
    float* sH  = (float*)(accHt + 16777216); // 262,144 f32 (1MB)
    u16* Wpk   = (u16*)(sH + 262144);        // 5,120 u16
    float* biasf = (float*)(Wpk + 5120);     // 80 f32

    wprep_kernel<<<1, 256, 0, stream>>>(Wq, bq, Wk, bk, Wv, bv, Wpk, biasf);
    proj_kernel<<<1024, 512, 0, stream>>>(x, Wpk, biasf, vb16, qkTr);
    vtrans_kernel<<<16384, 256, 0, stream>>>(vb16, vTc);
    colH_kernel<<<2048, 512, 0, stream>>>(qkTr, vTc, accHt, sH);
    rowW_fin_kernel<<<2048, 512, 0, stream>>>(qkTr, vb16, accHt, sH, x, gamma, out);
}